// Round 5
// baseline (2371.804 us; speedup 1.0000x reference)
//
#include <hip/hip_runtime.h>
#include <float.h>
#include <math.h>

#define Bg   8
#define NPGc 6250
#define Hh   4
#define Dd   128
#define Nn   50000
#define Ee   400000
#define HDd  512

__device__ __forceinline__ void atomicMaxF(float* addr, float val) {
    // ordered-int trick: works for mixed signs given IEEE-754 ordering
    if (val >= 0.0f) atomicMax((int*)addr, __float_as_int(val));
    else             atomicMin((unsigned int*)addr, __float_as_uint(val));
}

__global__ void init_kernel(float* m, float* denom, float* dout, float* din, float* pools) {
    int i = blockIdx.x * blockDim.x + threadIdx.x;
    if (i < Nn * Hh) { m[i] = -FLT_MAX; denom[i] = 0.0f; }
    if (i < Nn)      { dout[i] = 0.0f; din[i] = 0.0f; }
    if (i < Bg * 3 * Dd) pools[i] = -FLT_MAX;
}

__global__ void gather_kernel(const int* __restrict__ ids, const float* __restrict__ emb,
                              float* __restrict__ feat) {
    int i = blockIdx.x * blockDim.x + threadIdx.x;  // over N*32 float4s
    int n = i >> 5, c = i & 31;
    int id = ids[n];
    ((float4*)feat)[(size_t)n * 32 + c] = ((const float4*)emb)[(size_t)id * 32 + c];
}

// per-graph max over nodes for a [N,128] feature; blocks = (B, 50), 125 rows each
__global__ void maxpool_kernel(const float* __restrict__ x, float* __restrict__ pools, int col_off) {
    int b = blockIdx.x, chunk = blockIdx.y, d = threadIdx.x;
    int i0 = chunk * 125, i1 = i0 + 125;
    float mx = -FLT_MAX;
    for (int i = i0; i < i1; ++i)
        mx = fmaxf(mx, x[((size_t)(b * NPGc + i)) * Dd + d]);
    atomicMaxF(&pools[b * (3 * Dd) + col_off + d], mx);
}

// C[n,c] = leaky?( sum_k A[n,k]*scale(n) * W[k,c] + bias[c] )
// A:[n_rows,128], W:[128,WN], tile 64x64, 256 thr, 4x4 reg tile
__global__ __launch_bounds__(256) void gemm_kernel(
    const float* __restrict__ A, const float* __restrict__ W,
    const float* __restrict__ bias, float* __restrict__ C,
    int n_rows, int WN, const float* __restrict__ rowscale,
    int do_leak, float leak)
{
    __shared__ float As[64 * 132];   // padded stride 132
    __shared__ float Ws[64 * 64];    // one k-half at a time
    int row0 = blockIdx.x * 64;
    int col0 = blockIdx.y * 64;
    int tid  = threadIdx.x;

    // stage A tile: 64x128 = 8192 floats, 8 float4 per thread
    #pragma unroll
    for (int it = 0; it < 8; ++it) {
        int idx = (it * 256 + tid) * 4;
        int r = idx >> 7, c = idx & 127;
        int grow = row0 + r;
        float4 v = make_float4(0.f, 0.f, 0.f, 0.f);
        if (grow < n_rows) {
            v = *(const float4*)(A + (size_t)grow * 128 + c);
            if (rowscale) {
                float sc = 1.0f / sqrtf(fmaxf(rowscale[grow], 1.0f));
                v.x *= sc; v.y *= sc; v.z *= sc; v.w *= sc;
            }
        }
        *(float4*)(As + r * 132 + c) = v;
    }

    int tx = tid & 15, ty = tid >> 4;
    int r0 = ty * 4, c0 = tx * 4;
    float acc[4][4] = {};

    for (int kp = 0; kp < 2; ++kp) {
        __syncthreads();
        // stage W half: 64x64 = 4096 floats, 4 float4 per thread
        #pragma unroll
        for (int it = 0; it < 4; ++it) {
            int idx = (it * 256 + tid) * 4;
            int kk = idx >> 6, c = idx & 63;
            float4 v = *(const float4*)(W + (size_t)(kp * 64 + kk) * WN + col0 + c);
            *(float4*)(Ws + kk * 64 + c) = v;
        }
        __syncthreads();
        #pragma unroll 8
        for (int kk = 0; kk < 64; ++kk) {
            int k = kp * 64 + kk;
            float a[4];
            #pragma unroll
            for (int i = 0; i < 4; ++i) a[i] = As[(r0 + i) * 132 + k];
            float4 wv = *(const float4*)(Ws + kk * 64 + c0);
            float w[4] = {wv.x, wv.y, wv.z, wv.w};
            #pragma unroll
            for (int i = 0; i < 4; ++i)
                #pragma unroll
                for (int j = 0; j < 4; ++j)
                    acc[i][j] = fmaf(a[i], w[j], acc[i][j]);
        }
    }

    #pragma unroll
    for (int i = 0; i < 4; ++i) {
        int grow = row0 + r0 + i;
        if (grow >= n_rows) continue;
        float o[4];
        #pragma unroll
        for (int j = 0; j < 4; ++j) {
            float v = acc[i][j] + bias[col0 + c0 + j];
            if (do_leak) v = v >= 0.0f ? v : leak * v;
            o[j] = v;
        }
        *(float4*)(C + (size_t)grow * WN + col0 + c0) = *(float4*)o;
    }
}

// Pass A: one wave per edge; logits[e,h] = dot(leaky(hs[s]+hd[d],0.2), attn[h]); m = segmax
__global__ __launch_bounds__(256) void edge_logits_kernel(
    const float* __restrict__ hs, const float* __restrict__ hd,
    const int* __restrict__ src, const int* __restrict__ dst,
    const float* __restrict__ attn, float* __restrict__ logits, float* __restrict__ m)
{
    int w = (blockIdx.x * 256 + threadIdx.x) >> 6;
    int lane = threadIdx.x & 63;
    int s = src[w], d0 = dst[w];
    const float2* hsp = (const float2*)(hs + (size_t)s * HDd);
    const float2* hdp = (const float2*)(hd + (size_t)d0 * HDd);
    const float2* ap  = (const float2*)attn;
    #pragma unroll
    for (int h = 0; h < 4; ++h) {
        float2 a  = hsp[h * 64 + lane];
        float2 b  = hdp[h * 64 + lane];
        float2 at = ap[h * 64 + lane];
        float x0 = a.x + b.x; x0 = x0 >= 0.0f ? x0 : 0.2f * x0;
        float x1 = a.y + b.y; x1 = x1 >= 0.0f ? x1 : 0.2f * x1;
        float v = fmaf(x0, at.x, x1 * at.y);
        #pragma unroll
        for (int off = 32; off > 0; off >>= 1) v += __shfl_xor(v, off);
        if (lane == 0) {
            logits[(size_t)w * 4 + h] = v;
            atomicMaxF(&m[(size_t)d0 * 4 + h], v);
        }
    }
}

// Pass B: ex = exp(logit - m[dst]); denom[dst] += ex  (in-place over logits)
__global__ void edge_exp_kernel(const int* __restrict__ dst, float* __restrict__ logits,
                                const float* __restrict__ m, float* __restrict__ denom) {
    int i = blockIdx.x * blockDim.x + threadIdx.x;  // over E*4
    int e = i >> 2, h = i & 3;
    int d0 = dst[e];
    float ex = expf(logits[i] - m[(size_t)d0 * 4 + h]);
    logits[i] = ex;
    atomicAdd(&denom[(size_t)d0 * 4 + h], ex);
}

// Pass C: rst[dst] += hs[src] * alpha   (rst pre-initialized to x@W_res+b_res)
__global__ __launch_bounds__(256) void edge_aggregate_kernel(
    const float* __restrict__ hs, const float* __restrict__ ex, const float* __restrict__ denom,
    const int* __restrict__ src, const int* __restrict__ dst, float* __restrict__ rst)
{
    int w = (blockIdx.x * 256 + threadIdx.x) >> 6;
    int lane = threadIdx.x & 63;
    int s = src[w], d0 = dst[w];
    const float2* hsp = (const float2*)(hs + (size_t)s * HDd);
    float* rp = rst + (size_t)d0 * HDd;
    #pragma unroll
    for (int h = 0; h < 4; ++h) {
        float alpha = ex[(size_t)w * 4 + h] / denom[(size_t)d0 * 4 + h];
        float2 a = hsp[h * 64 + lane];
        atomicAdd(rp + h * 128 + 2 * lane,     a.x * alpha);
        atomicAdd(rp + h * 128 + 2 * lane + 1, a.y * alpha);
    }
}

// res[n,d] = mean_h leaky(rst[n,h,d], 0.01)
__global__ void head_mean_kernel(const float* __restrict__ rst, float* __restrict__ res) {
    int i = blockIdx.x * blockDim.x + threadIdx.x;  // N*128
    int n = i >> 7, d = i & 127;
    const float* r = rst + (size_t)n * HDd + d;
    float sum = 0.0f;
    #pragma unroll
    for (int h = 0; h < 4; ++h) {
        float v = r[h * 128];
        v = v >= 0.0f ? v : 0.01f * v;
        sum += v;
    }
    res[i] = 0.25f * sum;
}

__global__ void degree_kernel(const int* __restrict__ src, const int* __restrict__ dst,
                              float* __restrict__ dout, float* __restrict__ din) {
    int e = blockIdx.x * blockDim.x + threadIdx.x;
    if (e >= Ee) return;
    atomicAdd(&dout[src[e]], 1.0f);
    atomicAdd(&din[dst[e]], 1.0f);
}

// agg[dst] += res[src] * rsqrt(max(dout[src],1))
__global__ __launch_bounds__(256) void gc_agg_kernel(
    const float* __restrict__ res, const int* __restrict__ src, const int* __restrict__ dst,
    const float* __restrict__ dout, float* __restrict__ agg)
{
    int w = (blockIdx.x * 256 + threadIdx.x) >> 6;
    int lane = threadIdx.x & 63;
    int s = src[w], d0 = dst[w];
    float sc = 1.0f / sqrtf(fmaxf(dout[s], 1.0f));
    float2 a = ((const float2*)(res + (size_t)s * Dd))[lane];
    atomicAdd(agg + (size_t)d0 * Dd + 2 * lane,     a.x * sc);
    atomicAdd(agg + (size_t)d0 * Dd + 2 * lane + 1, a.y * sc);
}

// out[b] = relu(pools[b]) . W_mlp + b_mlp
__global__ void final_kernel(const float* __restrict__ pools, const float* __restrict__ W_mlp,
                             const float* __restrict__ b_mlp, float* __restrict__ out) {
    int b = blockIdx.x, lane = threadIdx.x;  // 64 threads
    float s = 0.0f;
    for (int j = lane; j < 3 * Dd; j += 64)
        s += fmaxf(pools[b * (3 * Dd) + j], 0.0f) * W_mlp[j];
    #pragma unroll
    for (int off = 32; off > 0; off >>= 1) s += __shfl_xor(s, off);
    if (lane == 0) out[b] = s + b_mlp[0];
}

extern "C" void kernel_launch(void* const* d_in, const int* in_sizes, int n_in,
                              void* d_out, int out_size, void* d_ws, size_t ws_size,
                              hipStream_t stream) {
    const int*   node_ids = (const int*)d_in[0];
    const int*   src      = (const int*)d_in[1];
    const int*   dst      = (const int*)d_in[2];
    const float* emb      = (const float*)d_in[3];
    const float* W_src    = (const float*)d_in[4];
    const float* b_src    = (const float*)d_in[5];
    const float* W_dst    = (const float*)d_in[6];
    const float* b_dst    = (const float*)d_in[7];
    const float* attn     = (const float*)d_in[8];
    const float* W_res    = (const float*)d_in[9];
    const float* b_res    = (const float*)d_in[10];
    const float* W_gc     = (const float*)d_in[11];
    const float* b_gc     = (const float*)d_in[12];
    const float* W_mlp    = (const float*)d_in[13];
    const float* b_mlp    = (const float*)d_in[14];
    float* out = (float*)d_out;

    float* ws = (float*)d_ws;
    size_t off = 0;
    float* feat   = ws + off; off += (size_t)Nn * Dd;    // reused as res later
    float* hs     = ws + off; off += (size_t)Nn * HDd;   // reused as agg + res2 later
    float* hd     = ws + off; off += (size_t)Nn * HDd;   // reused as rst later
    float* logits = ws + off; off += (size_t)Ee * Hh;    // reused as ex in-place
    float* m      = ws + off; off += (size_t)Nn * Hh;
    float* denom  = ws + off; off += (size_t)Nn * Hh;
    float* doutd  = ws + off; off += Nn;
    float* dind   = ws + off; off += Nn;
    float* pools  = ws + off; off += Bg * 3 * Dd;

    float* rst  = hd;                         // hd dead after edge_logits
    float* res  = feat;                       // feat dead after W_res GEMM
    float* agg  = hs;                         // hs dead after edge_aggregate
    float* res2 = hs + (size_t)Nn * Dd;

    init_kernel<<<(Nn * Hh + 255) / 256, 256, 0, stream>>>(m, denom, doutd, dind, pools);
    gather_kernel<<<(Nn * 32) / 256, 256, 0, stream>>>(node_ids, emb, feat);
    maxpool_kernel<<<dim3(Bg, 50), Dd, 0, stream>>>(feat, pools, 0);

    gemm_kernel<<<dim3(782, 8), 256, 0, stream>>>(feat, W_src, b_src, hs, Nn, HDd, nullptr, 0, 0.0f);
    gemm_kernel<<<dim3(782, 8), 256, 0, stream>>>(feat, W_dst, b_dst, hd, Nn, HDd, nullptr, 0, 0.0f);

    edge_logits_kernel<<<Ee / 4, 256, 0, stream>>>(hs, hd, src, dst, attn, logits, m);
    edge_exp_kernel<<<(Ee * Hh) / 256, 256, 0, stream>>>(dst, logits, m, denom);

    gemm_kernel<<<dim3(782, 8), 256, 0, stream>>>(feat, W_res, b_res, rst, Nn, HDd, nullptr, 0, 0.0f);
    edge_aggregate_kernel<<<Ee / 4, 256, 0, stream>>>(hs, logits, denom, src, dst, rst);

    head_mean_kernel<<<(Nn * Dd) / 256, 256, 0, stream>>>(rst, res);
    maxpool_kernel<<<dim3(Bg, 50), Dd, 0, stream>>>(res, pools, Dd);

    degree_kernel<<<(Ee + 255) / 256, 256, 0, stream>>>(src, dst, doutd, dind);
    hipMemsetAsync(agg, 0, (size_t)Nn * Dd * sizeof(float), stream);
    gc_agg_kernel<<<Ee / 4, 256, 0, stream>>>(res, src, dst, doutd, agg);
    gemm_kernel<<<dim3(782, 2), 256, 0, stream>>>(agg, W_gc, b_gc, res2, Nn, Dd, dind, 1, 0.01f);
    maxpool_kernel<<<dim3(Bg, 50), Dd, 0, stream>>>(res2, pools, 2 * Dd);

    final_kernel<<<Bg, 64, 0, stream>>>(pools, W_mlp, b_mlp, out);
}

// Round 6
// 716.148 us; speedup vs baseline: 3.3119x; 3.3119x over previous
//
#include <hip/hip_runtime.h>
#include <float.h>
#include <math.h>

#define Bg   8
#define NPGc 6250
#define Hh   4
#define Dd   128
#define Nn   50000
#define Ee   400000
#define HDd  512

typedef unsigned short ushort_t;

__device__ __forceinline__ void atomicMaxF(float* addr, float val) {
    if (val >= 0.0f) atomicMax((int*)addr, __float_as_int(val));
    else             atomicMin((unsigned int*)addr, __float_as_uint(val));
}

__device__ __forceinline__ ushort_t f2bf(float x) {
    unsigned u = __float_as_uint(x);
    unsigned r = (u + 0x7FFFu + ((u >> 16) & 1u)) >> 16;   // RNE
    return (ushort_t)r;
}

__device__ __forceinline__ void bf2x2(unsigned u, float& lo, float& hi) {
    lo = __uint_as_float(u << 16);
    hi = __uint_as_float(u & 0xFFFF0000u);
}

__global__ void init_kernel(int* din_i, float* dout, int* cursor, float* pools) {
    int i = blockIdx.x * blockDim.x + threadIdx.x;
    if (i < Nn) { din_i[i] = 0; dout[i] = 0.0f; cursor[i] = 0; }
    if (i < Bg * 3 * Dd) pools[i] = -FLT_MAX;
}

__global__ void gather_kernel(const int* __restrict__ ids, const float* __restrict__ emb,
                              float* __restrict__ feat) {
    int i = blockIdx.x * blockDim.x + threadIdx.x;  // over N*32 float4s
    int n = i >> 5, c = i & 31;
    int id = ids[n];
    ((float4*)feat)[(size_t)n * 32 + c] = ((const float4*)emb)[(size_t)id * 32 + c];
}

__global__ void maxpool_kernel(const float* __restrict__ x, float* __restrict__ pools, int col_off) {
    int b = blockIdx.x, chunk = blockIdx.y, d = threadIdx.x;
    int i0 = chunk * 125, i1 = i0 + 125;
    float mx = -FLT_MAX;
    for (int i = i0; i < i1; ++i)
        mx = fmaxf(mx, x[((size_t)(b * NPGc + i)) * Dd + d]);
    atomicMaxF(&pools[b * (3 * Dd) + col_off + d], mx);
}

// C[n,c] = leaky?( sum_k A[n,k]*scale(n) * W[k,c] + bias[c] ); optional bf16 output Cb
__global__ __launch_bounds__(256) void gemm_kernel(
    const float* __restrict__ A, const float* __restrict__ W,
    const float* __restrict__ bias, float* __restrict__ C, ushort_t* __restrict__ Cb,
    int n_rows, int WN, const float* __restrict__ rowscale,
    int do_leak, float leak)
{
    __shared__ float As[64 * 132];
    __shared__ float Ws[64 * 64];
    int row0 = blockIdx.x * 64;
    int col0 = blockIdx.y * 64;
    int tid  = threadIdx.x;

    #pragma unroll
    for (int it = 0; it < 8; ++it) {
        int idx = (it * 256 + tid) * 4;
        int r = idx >> 7, c = idx & 127;
        int grow = row0 + r;
        float4 v = make_float4(0.f, 0.f, 0.f, 0.f);
        if (grow < n_rows) {
            v = *(const float4*)(A + (size_t)grow * 128 + c);
            if (rowscale) {
                float sc = 1.0f / sqrtf(fmaxf(rowscale[grow], 1.0f));
                v.x *= sc; v.y *= sc; v.z *= sc; v.w *= sc;
            }
        }
        *(float4*)(As + r * 132 + c) = v;
    }

    int tx = tid & 15, ty = tid >> 4;
    int r0 = ty * 4, c0 = tx * 4;
    float acc[4][4] = {};

    for (int kp = 0; kp < 2; ++kp) {
        __syncthreads();
        #pragma unroll
        for (int it = 0; it < 4; ++it) {
            int idx = (it * 256 + tid) * 4;
            int kk = idx >> 6, c = idx & 63;
            float4 v = *(const float4*)(W + (size_t)(kp * 64 + kk) * WN + col0 + c);
            *(float4*)(Ws + kk * 64 + c) = v;
        }
        __syncthreads();
        #pragma unroll 8
        for (int kk = 0; kk < 64; ++kk) {
            int k = kp * 64 + kk;
            float a[4];
            #pragma unroll
            for (int i = 0; i < 4; ++i) a[i] = As[(r0 + i) * 132 + k];
            float4 wv = *(const float4*)(Ws + kk * 64 + c0);
            float w[4] = {wv.x, wv.y, wv.z, wv.w};
            #pragma unroll
            for (int i = 0; i < 4; ++i)
                #pragma unroll
                for (int j = 0; j < 4; ++j)
                    acc[i][j] = fmaf(a[i], w[j], acc[i][j]);
        }
    }

    #pragma unroll
    for (int i = 0; i < 4; ++i) {
        int grow = row0 + r0 + i;
        if (grow >= n_rows) continue;
        float o[4];
        #pragma unroll
        for (int j = 0; j < 4; ++j) {
            float v = acc[i][j] + bias[col0 + c0 + j];
            if (do_leak) v = v >= 0.0f ? v : leak * v;
            o[j] = v;
        }
        if (Cb) {
            ushort_t ob[4];
            #pragma unroll
            for (int j = 0; j < 4; ++j) ob[j] = f2bf(o[j]);
            *(ushort4*)(Cb + (size_t)grow * WN + col0 + c0) = *(ushort4*)ob;
        } else {
            *(float4*)(C + (size_t)grow * WN + col0 + c0) = *(float4*)o;
        }
    }
}

// ---- CSR build ----
__global__ void degree2_kernel(const int* __restrict__ src, const int* __restrict__ dst,
                               int* __restrict__ din_i, float* __restrict__ dout) {
    int e = blockIdx.x * blockDim.x + threadIdx.x;
    if (e >= Ee) return;
    atomicAdd(&din_i[dst[e]], 1);
    atomicAdd(&dout[src[e]], 1.0f);
}

// single-block exclusive scan over din_i -> row_start[N+1]; also din_f = (float)din_i
__global__ __launch_bounds__(1024) void scan_kernel(const int* __restrict__ din_i,
                                                    int* __restrict__ row_start,
                                                    float* __restrict__ din_f) {
    __shared__ int buf[1024];
    __shared__ int s_carry;
    int tid = threadIdx.x;
    if (tid == 0) s_carry = 0;
    __syncthreads();
    for (int base = 0; base < Nn; base += 1024) {
        int i = base + tid;
        int v = (i < Nn) ? din_i[i] : 0;
        buf[tid] = v;
        __syncthreads();
        #pragma unroll
        for (int off = 1; off < 1024; off <<= 1) {
            int t = (tid >= off) ? buf[tid - off] : 0;
            __syncthreads();
            buf[tid] += t;
            __syncthreads();
        }
        if (i < Nn) {
            row_start[i] = s_carry + buf[tid] - v;   // exclusive
            din_f[i] = (float)v;
        }
        int total = buf[1023];
        __syncthreads();
        if (tid == 0) s_carry += total;
        __syncthreads();
    }
    if (tid == 0) row_start[Nn] = s_carry;
}

__global__ void scatter_kernel(const int* __restrict__ src, const int* __restrict__ dst,
                               const int* __restrict__ row_start, int* __restrict__ cursor,
                               int* __restrict__ csr_src) {
    int e = blockIdx.x * blockDim.x + threadIdx.x;
    if (e >= Ee) return;
    int d = dst[e];
    int slot = row_start[d] + atomicAdd(&cursor[d], 1);
    csr_src[slot] = src[e];
}

// ---- fused GATv2: one wave per dst node, online softmax over in-edges ----
// lane l owns flat columns [8l, 8l+8) of the 512-wide row => head = l>>4
__global__ __launch_bounds__(256) void gat_fused_kernel(
    const ushort_t* __restrict__ hs, const ushort_t* __restrict__ hd,
    const ushort_t* __restrict__ rstres, const float* __restrict__ attn,
    const int* __restrict__ row_start, const int* __restrict__ csr_src,
    float* __restrict__ res)
{
    int d = (blockIdx.x * 256 + threadIdx.x) >> 6;
    int lane = threadIdx.x & 63;
    if (d >= Nn) return;
    int e0 = row_start[d], e1 = row_start[d + 1];

    float hdv[8], atv[8];
    {
        uint4 hr = *(const uint4*)(hd + (size_t)d * HDd + lane * 8);
        bf2x2(hr.x, hdv[0], hdv[1]); bf2x2(hr.y, hdv[2], hdv[3]);
        bf2x2(hr.z, hdv[4], hdv[5]); bf2x2(hr.w, hdv[6], hdv[7]);
        float4 a0 = *(const float4*)(attn + lane * 8);
        float4 a1 = *(const float4*)(attn + lane * 8 + 4);
        atv[0] = a0.x; atv[1] = a0.y; atv[2] = a0.z; atv[3] = a0.w;
        atv[4] = a1.x; atv[5] = a1.y; atv[6] = a1.z; atv[7] = a1.w;
    }

    float m = -FLT_MAX, denom = 0.0f;
    float acc[8] = {};

    int s = (e0 < e1) ? csr_src[e0] : 0;
    for (int e = e0; e < e1; ++e) {
        int s_next = (e + 1 < e1) ? csr_src[e + 1] : 0;
        uint4 raw = *(const uint4*)(hs + (size_t)s * HDd + lane * 8);
        float hsv[8];
        bf2x2(raw.x, hsv[0], hsv[1]); bf2x2(raw.y, hsv[2], hsv[3]);
        bf2x2(raw.z, hsv[4], hsv[5]); bf2x2(raw.w, hsv[6], hsv[7]);
        float p = 0.0f;
        #pragma unroll
        for (int j = 0; j < 8; ++j) {
            float x = hsv[j] + hdv[j];
            x = x >= 0.0f ? x : 0.2f * x;
            p = fmaf(x, atv[j], p);
        }
        // reduce within 16-lane head group
        p += __shfl_xor(p, 1); p += __shfl_xor(p, 2);
        p += __shfl_xor(p, 4); p += __shfl_xor(p, 8);
        float mn = fmaxf(m, p);
        float corr = expf(m - mn);
        float ex = expf(p - mn);
        denom = denom * corr + ex;
        #pragma unroll
        for (int j = 0; j < 8; ++j) acc[j] = fmaf(acc[j], corr, hsv[j] * ex);
        m = mn;
        s = s_next;
    }

    float inv = (e1 > e0) ? 1.0f / denom : 0.0f;
    float rv[8];
    {
        uint4 rr = *(const uint4*)(rstres + (size_t)d * HDd + lane * 8);
        bf2x2(rr.x, rv[0], rv[1]); bf2x2(rr.y, rv[2], rv[3]);
        bf2x2(rr.z, rv[4], rv[5]); bf2x2(rr.w, rv[6], rv[7]);
    }
    float t[8];
    #pragma unroll
    for (int j = 0; j < 8; ++j) {
        float v = fmaf(acc[j], inv, rv[j]);
        t[j] = v >= 0.0f ? v : 0.01f * v;
    }
    // mean over heads: lanes l, l^16, l^32, l^48 hold same column of the 4 heads
    #pragma unroll
    for (int j = 0; j < 8; ++j) {
        t[j] += __shfl_xor(t[j], 16);
        t[j] += __shfl_xor(t[j], 32);
    }
    if (lane < 16) {
        float o0[4] = {0.25f * t[0], 0.25f * t[1], 0.25f * t[2], 0.25f * t[3]};
        float o1[4] = {0.25f * t[4], 0.25f * t[5], 0.25f * t[6], 0.25f * t[7]};
        *(float4*)(res + (size_t)d * Dd + lane * 8)     = *(float4*)o0;
        *(float4*)(res + (size_t)d * Dd + lane * 8 + 4) = *(float4*)o1;
    }
}

// ---- GraphConv aggregate via CSR: one wave per dst ----
__global__ __launch_bounds__(256) void gc_gather_kernel(
    const float* __restrict__ res, const int* __restrict__ row_start,
    const int* __restrict__ csr_src, const float* __restrict__ dout,
    float* __restrict__ agg)
{
    int d = (blockIdx.x * 256 + threadIdx.x) >> 6;
    int lane = threadIdx.x & 63;
    if (d >= Nn) return;
    int e0 = row_start[d], e1 = row_start[d + 1];
    float ax = 0.0f, ay = 0.0f;
    int s = (e0 < e1) ? csr_src[e0] : 0;
    for (int e = e0; e < e1; ++e) {
        int s_next = (e + 1 < e1) ? csr_src[e + 1] : 0;
        float sc = 1.0f / sqrtf(fmaxf(dout[s], 1.0f));
        float2 v = ((const float2*)(res + (size_t)s * Dd))[lane];
        ax = fmaf(v.x, sc, ax);
        ay = fmaf(v.y, sc, ay);
        s = s_next;
    }
    float2 o; o.x = ax; o.y = ay;
    ((float2*)(agg + (size_t)d * Dd))[lane] = o;
}

__global__ void final_kernel(const float* __restrict__ pools, const float* __restrict__ W_mlp,
                             const float* __restrict__ b_mlp, float* __restrict__ out) {
    int b = blockIdx.x, lane = threadIdx.x;
    float s = 0.0f;
    for (int j = lane; j < 3 * Dd; j += 64)
        s += fmaxf(pools[b * (3 * Dd) + j], 0.0f) * W_mlp[j];
    #pragma unroll
    for (int off = 32; off > 0; off >>= 1) s += __shfl_xor(s, off);
    if (lane == 0) out[b] = s + b_mlp[0];
}

extern "C" void kernel_launch(void* const* d_in, const int* in_sizes, int n_in,
                              void* d_out, int out_size, void* d_ws, size_t ws_size,
                              hipStream_t stream) {
    const int*   node_ids = (const int*)d_in[0];
    const int*   src      = (const int*)d_in[1];
    const int*   dst      = (const int*)d_in[2];
    const float* emb      = (const float*)d_in[3];
    const float* W_src    = (const float*)d_in[4];
    const float* b_src    = (const float*)d_in[5];
    const float* W_dst    = (const float*)d_in[6];
    const float* b_dst    = (const float*)d_in[7];
    const float* attn     = (const float*)d_in[8];
    const float* W_res    = (const float*)d_in[9];
    const float* b_res    = (const float*)d_in[10];
    const float* W_gc     = (const float*)d_in[11];
    const float* b_gc     = (const float*)d_in[12];
    const float* W_mlp    = (const float*)d_in[13];
    const float* b_mlp    = (const float*)d_in[14];
    float* out = (float*)d_out;

    char* w = (char*)d_ws;
    const size_t SZ_FEAT = (size_t)Nn * Dd * 4;      // 25.6 MB (f32)
    const size_t SZ_H    = (size_t)Nn * HDd * 2;     // 51.2 MB (bf16)
    size_t off = 0;
    float*    feat    = (float*)(w + off);    off += SZ_FEAT;
    ushort_t* hs_b    = (ushort_t*)(w + off); off += SZ_H;
    ushort_t* hd_b    = (ushort_t*)(w + off); off += SZ_H;
    ushort_t* rres_b  = (ushort_t*)(w + off); off += SZ_H;
    int*      csr_src = (int*)(w + off);      off += (size_t)Ee * 4;
    int*      row_st  = (int*)(w + off);      off += ((size_t)Nn + 4) * 4;
    int*      cursor  = (int*)(w + off);      off += (size_t)Nn * 4;
    int*      din_i   = (int*)(w + off);      off += (size_t)Nn * 4;
    float*    din_f   = (float*)(w + off);    off += (size_t)Nn * 4;
    float*    dout_f  = (float*)(w + off);    off += (size_t)Nn * 4;
    float*    pools   = (float*)(w + off);    off += (size_t)Bg * 3 * Dd * 4;

    float* res  = feat;                        // feat dead after 3rd GEMM
    float* agg  = (float*)hs_b;                // hs dead after gat_fused
    float* res2 = (float*)hs_b + (size_t)Nn * Dd;

    init_kernel<<<(Nn + 255) / 256, 256, 0, stream>>>(din_i, dout_f, cursor, pools);
    gather_kernel<<<(Nn * 32) / 256, 256, 0, stream>>>(node_ids, emb, feat);
    maxpool_kernel<<<dim3(Bg, 50), Dd, 0, stream>>>(feat, pools, 0);

    // CSR build (independent of GEMMs, stream-ordered anyway)
    degree2_kernel<<<(Ee + 255) / 256, 256, 0, stream>>>(src, dst, din_i, dout_f);
    scan_kernel<<<1, 1024, 0, stream>>>(din_i, row_st, din_f);
    scatter_kernel<<<(Ee + 255) / 256, 256, 0, stream>>>(src, dst, row_st, cursor, csr_src);

    gemm_kernel<<<dim3(782, 8), 256, 0, stream>>>(feat, W_src, b_src, nullptr, hs_b,  Nn, HDd, nullptr, 0, 0.0f);
    gemm_kernel<<<dim3(782, 8), 256, 0, stream>>>(feat, W_dst, b_dst, nullptr, hd_b,  Nn, HDd, nullptr, 0, 0.0f);
    gemm_kernel<<<dim3(782, 8), 256, 0, stream>>>(feat, W_res, b_res, nullptr, rres_b, Nn, HDd, nullptr, 0, 0.0f);

    gat_fused_kernel<<<(Nn * 64) / 256, 256, 0, stream>>>(hs_b, hd_b, rres_b, attn, row_st, csr_src, res);
    maxpool_kernel<<<dim3(Bg, 50), Dd, 0, stream>>>(res, pools, Dd);

    gc_gather_kernel<<<(Nn * 64) / 256, 256, 0, stream>>>(res, row_st, csr_src, dout_f, agg);
    gemm_kernel<<<dim3(782, 2), 256, 0, stream>>>(agg, W_gc, b_gc, res2, nullptr, Nn, Dd, din_f, 1, 0.01f);
    maxpool_kernel<<<dim3(Bg, 50), Dd, 0, stream>>>(res2, pools, 2 * Dd);

    final_kernel<<<Bg, 64, 0, stream>>>(pools, W_mlp, b_mlp, out);
}

// Round 7
// 519.267 us; speedup vs baseline: 4.5676x; 1.3792x over previous
//
#include <hip/hip_runtime.h>
#include <float.h>
#include <math.h>

#define Bg   8
#define NPGc 6250
#define Hh   4
#define Dd   128
#define Nn   50000
#define Ee   400000
#define HDd  512
#define WNf  1536   // fused hs|hd|rres width

typedef unsigned short ushort_t;
typedef __attribute__((ext_vector_type(8))) short bf16x8;
typedef __attribute__((ext_vector_type(4))) float f32x4;

__device__ __forceinline__ void atomicMaxF(float* addr, float val) {
    if (val >= 0.0f) atomicMax((int*)addr, __float_as_int(val));
    else             atomicMin((unsigned int*)addr, __float_as_uint(val));
}

__device__ __forceinline__ ushort_t f2bf(float x) {
    unsigned u = __float_as_uint(x);
    unsigned r = (u + 0x7FFFu + ((u >> 16) & 1u)) >> 16;   // RNE
    return (ushort_t)r;
}

__device__ __forceinline__ void bf2x2(unsigned u, float& lo, float& hi) {
    lo = __uint_as_float(u << 16);
    hi = __uint_as_float(u & 0xFFFF0000u);
}

__global__ void init_kernel(int* din_i, float* dout, int* cursor, float* pools) {
    int i = blockIdx.x * blockDim.x + threadIdx.x;
    if (i < Nn) { din_i[i] = 0; dout[i] = 0.0f; cursor[i] = 0; }
    if (i < Bg * 3 * Dd) pools[i] = -FLT_MAX;
}

__global__ void gather_kernel(const int* __restrict__ ids, const float* __restrict__ emb,
                              float* __restrict__ feat, ushort_t* __restrict__ feat_bf) {
    int i = blockIdx.x * blockDim.x + threadIdx.x;  // over N*32 float4s
    int n = i >> 5, c = i & 31;
    int id = ids[n];
    float4 v = ((const float4*)emb)[(size_t)id * 32 + c];
    ((float4*)feat)[(size_t)n * 32 + c] = v;
    ushort4 b;
    b.x = f2bf(v.x); b.y = f2bf(v.y); b.z = f2bf(v.z); b.w = f2bf(v.w);
    ((ushort4*)feat_bf)[(size_t)n * 32 + c] = b;
}

__global__ void maxpool_kernel(const float* __restrict__ x, float* __restrict__ pools, int col_off) {
    int b = blockIdx.x, chunk = blockIdx.y, d = threadIdx.x;
    int i0 = chunk * 125, i1 = i0 + 125;
    float mx = -FLT_MAX;
    for (int i = i0; i < i1; ++i)
        mx = fmaxf(mx, x[((size_t)(b * NPGc + i)) * Dd + d]);
    atomicMaxF(&pools[b * (3 * Dd) + col_off + d], mx);
}

// Build Wt [1536][128] bf16 (fused W_src|W_dst|W_res transposed), Wt_gc [128][128] bf16, bias_f[1536]
__global__ void prep_kernel(const float* __restrict__ W_src, const float* __restrict__ W_dst,
                            const float* __restrict__ W_res, const float* __restrict__ W_gc,
                            const float* __restrict__ b_src, const float* __restrict__ b_dst,
                            const float* __restrict__ b_res,
                            ushort_t* __restrict__ Wt, ushort_t* __restrict__ Wt_gc,
                            float* __restrict__ bias_f) {
    int i = blockIdx.x * blockDim.x + threadIdx.x;
    if (i < WNf * 128) {
        int c = i >> 7, k = i & 127;
        float v = (c < 512) ? W_src[k * 512 + c]
                : (c < 1024) ? W_dst[k * 512 + (c - 512)]
                             : W_res[k * 512 + (c - 1024)];
        Wt[i] = f2bf(v);
    } else if (i < WNf * 128 + 128 * 128) {
        int j = i - WNf * 128;
        int c = j >> 7, k = j & 127;
        Wt_gc[j] = f2bf(W_gc[k * 128 + c]);
    }
    if (i < WNf)
        bias_f[i] = (i < 512) ? b_src[i] : (i < 1024) ? b_dst[i - 512] : b_res[i - 1024];
}

// ---- MFMA GEMM: C[n,c] = act( A[n,:] @ Wt[c,:] + bias[c] ) ----
// A [n_rows][128] bf16, Wt [WN][128] bf16 (pre-transposed). Tile 128 rows x 64 cols.
// 4 waves, each 64x32 (4x2 fragments of 16x16, 4 K-steps of 32).
#define LDA 136   // padded bf16 elems/row (272 B): bank stride 4 dwords -> conflict-free b128 frag reads
__global__ __launch_bounds__(256) void mfma_gemm_kernel(
    const ushort_t* __restrict__ A, const ushort_t* __restrict__ Wt,
    const float* __restrict__ bias, ushort_t* __restrict__ Ob, float* __restrict__ Of,
    int n_rows, int WN, int do_leak)
{
    __shared__ ushort_t As[128 * LDA];   // 34816 B
    __shared__ ushort_t Bs[64 * LDA];    // 17408 B
    int col0 = blockIdx.x * 64;          // col index fastest -> consecutive blocks share A tile
    int row0 = blockIdx.y * 128;
    int tid  = threadIdx.x;

    {   // stage A: 2 threads/row, 8 x uint4 each
        int r = tid >> 1, hf = tid & 1;
        int grow = row0 + r;
        const uint4* gp = (const uint4*)(A + (size_t)grow * 128 + hf * 64);
        uint4 t[8];
        if (grow < n_rows) {
            #pragma unroll
            for (int i = 0; i < 8; ++i) t[i] = gp[i];
        } else {
            #pragma unroll
            for (int i = 0; i < 8; ++i) t[i] = make_uint4(0, 0, 0, 0);
        }
        uint4* lp = (uint4*)(As + r * LDA + hf * 64);
        #pragma unroll
        for (int i = 0; i < 8; ++i) lp[i] = t[i];
    }
    {   // stage B: 4 threads/row, 4 x uint4 each
        int r = tid >> 2, q = tid & 3;
        const uint4* gp = (const uint4*)(Wt + (size_t)(col0 + r) * 128 + q * 32);
        uint4 t[4];
        #pragma unroll
        for (int i = 0; i < 4; ++i) t[i] = gp[i];
        uint4* lp = (uint4*)(Bs + r * LDA + q * 32);
        #pragma unroll
        for (int i = 0; i < 4; ++i) lp[i] = t[i];
    }
    __syncthreads();

    int wv = tid >> 6, lane = tid & 63;
    int wr = wv >> 1, wc = wv & 1;       // wave tile: rows wr*64, cols wc*32
    int lrow = lane & 15, kg = lane >> 4;

    f32x4 acc[4][2] = {};
    #pragma unroll
    for (int ks = 0; ks < 4; ++ks) {
        int koff = ks * 32 + kg * 8;
        bf16x8 av[4], bv[2];
        #pragma unroll
        for (int fi = 0; fi < 4; ++fi)
            av[fi] = *(const bf16x8*)(As + (wr * 64 + fi * 16 + lrow) * LDA + koff);
        #pragma unroll
        for (int fj = 0; fj < 2; ++fj)
            bv[fj] = *(const bf16x8*)(Bs + (wc * 32 + fj * 16 + lrow) * LDA + koff);
        #pragma unroll
        for (int fi = 0; fi < 4; ++fi)
            #pragma unroll
            for (int fj = 0; fj < 2; ++fj)
                acc[fi][fj] = __builtin_amdgcn_mfma_f32_16x16x32_bf16(av[fi], bv[fj], acc[fi][fj], 0, 0, 0);
    }

    // epilogue: D lane mapping col = lane&15, row = (lane>>4)*4 + j
    #pragma unroll
    for (int fj = 0; fj < 2; ++fj) {
        int col = col0 + wc * 32 + fj * 16 + lrow;
        float bval = bias[col];
        #pragma unroll
        for (int fi = 0; fi < 4; ++fi) {
            #pragma unroll
            for (int j = 0; j < 4; ++j) {
                int grow = row0 + wr * 64 + fi * 16 + kg * 4 + j;
                if (grow >= n_rows) continue;
                float v = acc[fi][fj][j] + bval;
                if (do_leak) v = v >= 0.0f ? v : 0.01f * v;
                if (Ob) Ob[(size_t)grow * WN + col] = f2bf(v);
                else    Of[(size_t)grow * WN + col] = v;
            }
        }
    }
}

// ---- CSR build ----
__global__ void degree2_kernel(const int* __restrict__ src, const int* __restrict__ dst,
                               int* __restrict__ din_i, float* __restrict__ dout) {
    int e = blockIdx.x * blockDim.x + threadIdx.x;
    if (e >= Ee) return;
    atomicAdd(&din_i[dst[e]], 1);
    atomicAdd(&dout[src[e]], 1.0f);
}

__global__ __launch_bounds__(1024) void scan_kernel(const int* __restrict__ din_i,
                                                    int* __restrict__ row_start,
                                                    float* __restrict__ din_f) {
    __shared__ int buf[1024];
    __shared__ int s_carry;
    int tid = threadIdx.x;
    if (tid == 0) s_carry = 0;
    __syncthreads();
    for (int base = 0; base < Nn; base += 1024) {
        int i = base + tid;
        int v = (i < Nn) ? din_i[i] : 0;
        buf[tid] = v;
        __syncthreads();
        #pragma unroll
        for (int off = 1; off < 1024; off <<= 1) {
            int t = (tid >= off) ? buf[tid - off] : 0;
            __syncthreads();
            buf[tid] += t;
            __syncthreads();
        }
        if (i < Nn) {
            row_start[i] = s_carry + buf[tid] - v;   // exclusive
            din_f[i] = (float)v;
        }
        int total = buf[1023];
        __syncthreads();
        if (tid == 0) s_carry += total;
        __syncthreads();
    }
    if (tid == 0) row_start[Nn] = s_carry;
}

__global__ void scatter_kernel(const int* __restrict__ src, const int* __restrict__ dst,
                               const int* __restrict__ row_start, int* __restrict__ cursor,
                               int* __restrict__ csr_src) {
    int e = blockIdx.x * blockDim.x + threadIdx.x;
    if (e >= Ee) return;
    int d = dst[e];
    int slot = row_start[d] + atomicAdd(&cursor[d], 1);
    csr_src[slot] = src[e];
}

// ---- fused GATv2: one wave per dst node, online softmax over in-edges ----
// h_all row: [hs(512) | hd(512) | rres(512)] bf16. lane l owns flat cols [8l,8l+8), head = l>>4
__global__ __launch_bounds__(256) void gat_fused_kernel(
    const ushort_t* __restrict__ h_all, const float* __restrict__ attn,
    const int* __restrict__ row_start, const int* __restrict__ csr_src,
    float* __restrict__ res)
{
    int d = (blockIdx.x * 256 + threadIdx.x) >> 6;
    int lane = threadIdx.x & 63;
    if (d >= Nn) return;
    int e0 = row_start[d], e1 = row_start[d + 1];

    float hdv[8], atv[8];
    {
        uint4 hr = *(const uint4*)(h_all + (size_t)d * WNf + 512 + lane * 8);
        bf2x2(hr.x, hdv[0], hdv[1]); bf2x2(hr.y, hdv[2], hdv[3]);
        bf2x2(hr.z, hdv[4], hdv[5]); bf2x2(hr.w, hdv[6], hdv[7]);
        float4 a0 = *(const float4*)(attn + lane * 8);
        float4 a1 = *(const float4*)(attn + lane * 8 + 4);
        atv[0] = a0.x; atv[1] = a0.y; atv[2] = a0.z; atv[3] = a0.w;
        atv[4] = a1.x; atv[5] = a1.y; atv[6] = a1.z; atv[7] = a1.w;
    }

    float m = -FLT_MAX, denom = 0.0f;
    float acc[8] = {};

    int s = (e0 < e1) ? csr_src[e0] : 0;
    for (int e = e0; e < e1; ++e) {
        int s_next = (e + 1 < e1) ? csr_src[e + 1] : 0;
        uint4 raw = *(const uint4*)(h_all + (size_t)s * WNf + lane * 8);
        float hsv[8];
        bf2x2(raw.x, hsv[0], hsv[1]); bf2x2(raw.y, hsv[2], hsv[3]);
        bf2x2(raw.z, hsv[4], hsv[5]); bf2x2(raw.w, hsv[6], hsv[7]);
        float p = 0.0f;
        #pragma unroll
        for (int j = 0; j < 8; ++j) {
            float x = hsv[j] + hdv[j];
            x = x >= 0.0f ? x : 0.2f * x;
            p = fmaf(x, atv[j], p);
        }
        p += __shfl_xor(p, 1); p += __shfl_xor(p, 2);
        p += __shfl_xor(p, 4); p += __shfl_xor(p, 8);
        float mn = fmaxf(m, p);
        float corr = expf(m - mn);
        float ex = expf(p - mn);
        denom = denom * corr + ex;
        #pragma unroll
        for (int j = 0; j < 8; ++j) acc[j] = fmaf(acc[j], corr, hsv[j] * ex);
        m = mn;
        s = s_next;
    }

    float inv = (e1 > e0) ? 1.0f / denom : 0.0f;
    float rv[8];
    {
        uint4 rr = *(const uint4*)(h_all + (size_t)d * WNf + 1024 + lane * 8);
        bf2x2(rr.x, rv[0], rv[1]); bf2x2(rr.y, rv[2], rv[3]);
        bf2x2(rr.z, rv[4], rv[5]); bf2x2(rr.w, rv[6], rv[7]);
    }
    float t[8];
    #pragma unroll
    for (int j = 0; j < 8; ++j) {
        float v = fmaf(acc[j], inv, rv[j]);
        t[j] = v >= 0.0f ? v : 0.01f * v;
    }
    #pragma unroll
    for (int j = 0; j < 8; ++j) {
        t[j] += __shfl_xor(t[j], 16);
        t[j] += __shfl_xor(t[j], 32);
    }
    if (lane < 16) {
        float o0[4] = {0.25f * t[0], 0.25f * t[1], 0.25f * t[2], 0.25f * t[3]};
        float o1[4] = {0.25f * t[4], 0.25f * t[5], 0.25f * t[6], 0.25f * t[7]};
        *(float4*)(res + (size_t)d * Dd + lane * 8)     = *(float4*)o0;
        *(float4*)(res + (size_t)d * Dd + lane * 8 + 4) = *(float4*)o1;
    }
}

// ---- GraphConv aggregate via CSR; epilogue applies rsqrt(din) and emits bf16 ----
__global__ __launch_bounds__(256) void gc_gather_kernel(
    const float* __restrict__ res, const int* __restrict__ row_start,
    const int* __restrict__ csr_src, const float* __restrict__ dout,
    const float* __restrict__ din, ushort_t* __restrict__ agg_bf)
{
    int d = (blockIdx.x * 256 + threadIdx.x) >> 6;
    int lane = threadIdx.x & 63;
    if (d >= Nn) return;
    int e0 = row_start[d], e1 = row_start[d + 1];
    float ax = 0.0f, ay = 0.0f;
    int s = (e0 < e1) ? csr_src[e0] : 0;
    for (int e = e0; e < e1; ++e) {
        int s_next = (e + 1 < e1) ? csr_src[e + 1] : 0;
        float sc = 1.0f / sqrtf(fmaxf(dout[s], 1.0f));
        float2 v = ((const float2*)(res + (size_t)s * Dd))[lane];
        ax = fmaf(v.x, sc, ax);
        ay = fmaf(v.y, sc, ay);
        s = s_next;
    }
    float scd = 1.0f / sqrtf(fmaxf(din[d], 1.0f));
    ushort2 o;
    o.x = f2bf(ax * scd);
    o.y = f2bf(ay * scd);
    ((ushort2*)(agg_bf + (size_t)d * Dd))[lane] = o;
}

__global__ void final_kernel(const float* __restrict__ pools, const float* __restrict__ W_mlp,
                             const float* __restrict__ b_mlp, float* __restrict__ out) {
    int b = blockIdx.x, lane = threadIdx.x;
    float s = 0.0f;
    for (int j = lane; j < 3 * Dd; j += 64)
        s += fmaxf(pools[b * (3 * Dd) + j], 0.0f) * W_mlp[j];
    #pragma unroll
    for (int off = 32; off > 0; off >>= 1) s += __shfl_xor(s, off);
    if (lane == 0) out[b] = s + b_mlp[0];
}

extern "C" void kernel_launch(void* const* d_in, const int* in_sizes, int n_in,
                              void* d_out, int out_size, void* d_ws, size_t ws_size,
                              hipStream_t stream) {
    const int*   node_ids = (const int*)d_in[0];
    const int*   src      = (const int*)d_in[1];
    const int*   dst      = (const int*)d_in[2];
    const float* emb      = (const float*)d_in[3];
    const float* W_src    = (const float*)d_in[4];
    const float* b_src    = (const float*)d_in[5];
    const float* W_dst    = (const float*)d_in[6];
    const float* b_dst    = (const float*)d_in[7];
    const float* attn     = (const float*)d_in[8];
    const float* W_res    = (const float*)d_in[9];
    const float* b_res    = (const float*)d_in[10];
    const float* W_gc     = (const float*)d_in[11];
    const float* b_gc     = (const float*)d_in[12];
    const float* W_mlp    = (const float*)d_in[13];
    const float* b_mlp    = (const float*)d_in[14];
    float* out = (float*)d_out;

    char* w = (char*)d_ws;
    size_t off = 0;
    float*    feat    = (float*)(w + off);    off += (size_t)Nn * Dd * 4;        // 25.6 MB
    ushort_t* feat_bf = (ushort_t*)(w + off); off += (size_t)Nn * Dd * 2;        // 12.8 MB
    ushort_t* h_all   = (ushort_t*)(w + off); off += (size_t)Nn * WNf * 2;       // 153.6 MB
    ushort_t* Wt      = (ushort_t*)(w + off); off += (size_t)WNf * 128 * 2;
    ushort_t* Wt_gc   = (ushort_t*)(w + off); off += (size_t)128 * 128 * 2;
    float*    bias_f  = (float*)(w + off);    off += (size_t)WNf * 4;
    int*      csr_src = (int*)(w + off);      off += (size_t)Ee * 4;
    int*      row_st  = (int*)(w + off);      off += ((size_t)Nn + 4) * 4;
    int*      cursor  = (int*)(w + off);      off += (size_t)Nn * 4;
    int*      din_i   = (int*)(w + off);      off += (size_t)Nn * 4;
    float*    din_f   = (float*)(w + off);    off += (size_t)Nn * 4;
    float*    dout_f  = (float*)(w + off);    off += (size_t)Nn * 4;
    float*    pools   = (float*)(w + off);    off += (size_t)Bg * 3 * Dd * 4;

    float*    res    = feat;                                  // feat dead after fused GEMM
    ushort_t* agg_bf = h_all;                                 // h_all dead after gat_fused
    float*    res2   = (float*)(w + (size_t)Nn * Dd * 6 + (size_t)Nn * Dd * 2);  // inside h_all, past agg_bf

    init_kernel<<<(Nn + 255) / 256, 256, 0, stream>>>(din_i, dout_f, cursor, pools);
    gather_kernel<<<(Nn * 32) / 256, 256, 0, stream>>>(node_ids, emb, feat, feat_bf);
    maxpool_kernel<<<dim3(Bg, 50), Dd, 0, stream>>>(feat, pools, 0);

    prep_kernel<<<(WNf * 128 + 128 * 128 + 255) / 256, 256, 0, stream>>>(
        W_src, W_dst, W_res, W_gc, b_src, b_dst, b_res, Wt, Wt_gc, bias_f);

    // CSR build
    degree2_kernel<<<(Ee + 255) / 256, 256, 0, stream>>>(src, dst, din_i, dout_f);
    scan_kernel<<<1, 1024, 0, stream>>>(din_i, row_st, din_f);
    scatter_kernel<<<(Ee + 255) / 256, 256, 0, stream>>>(src, dst, row_st, cursor, csr_src);

    // fused hs|hd|rres GEMM via MFMA
    mfma_gemm_kernel<<<dim3(WNf / 64, (Nn + 127) / 128), 256, 0, stream>>>(
        feat_bf, Wt, bias_f, h_all, nullptr, Nn, WNf, 0);

    gat_fused_kernel<<<(Nn * 64) / 256, 256, 0, stream>>>(h_all, attn, row_st, csr_src, res);
    maxpool_kernel<<<dim3(Bg, 50), Dd, 0, stream>>>(res, pools, Dd);

    gc_gather_kernel<<<(Nn * 64) / 256, 256, 0, stream>>>(res, row_st, csr_src, dout_f, din_f, agg_bf);
    mfma_gemm_kernel<<<dim3(128 / 64, (Nn + 127) / 128), 256, 0, stream>>>(
        agg_bf, Wt_gc, b_gc, nullptr, res2, Nn, Dd, 1);
    maxpool_kernel<<<dim3(Bg, 50), Dd, 0, stream>>>(res2, pools, 2 * Dd);

    final_kernel<<<Bg, 64, 0, stream>>>(pools, W_mlp, b_mlp, out);
}

// Round 8
// 460.533 us; speedup vs baseline: 5.1501x; 1.1275x over previous
//
#include <hip/hip_runtime.h>
#include <float.h>
#include <math.h>

#define Bg   8
#define NPGc 6250
#define Hh   4
#define Dd   128
#define Nn   50000
#define Ee   400000
#define HDd  512
#define WNf  1536   // fused hs|hd|rres width
#define NCHUNK 49   // ceil(50000/1024)

typedef unsigned short ushort_t;
typedef __attribute__((ext_vector_type(8))) short bf16x8;
typedef __attribute__((ext_vector_type(4))) float f32x4;

__device__ __forceinline__ void atomicMaxF(float* addr, float val) {
    if (val >= 0.0f) atomicMax((int*)addr, __float_as_int(val));
    else             atomicMin((unsigned int*)addr, __float_as_uint(val));
}

__device__ __forceinline__ ushort_t f2bf(float x) {
    unsigned u = __float_as_uint(x);
    unsigned r = (u + 0x7FFFu + ((u >> 16) & 1u)) >> 16;   // RNE
    return (ushort_t)r;
}

__device__ __forceinline__ void bf2x2(unsigned u, float& lo, float& hi) {
    lo = __uint_as_float(u << 16);
    hi = __uint_as_float(u & 0xFFFF0000u);
}

__global__ void init_kernel(int* din_i, float* dout, int* cursor, float* pools) {
    int i = blockIdx.x * blockDim.x + threadIdx.x;
    if (i < Nn) { din_i[i] = 0; dout[i] = 0.0f; cursor[i] = 0; }
    if (i < Bg * 3 * Dd) pools[i] = -FLT_MAX;
}

__global__ void gather_kernel(const int* __restrict__ ids, const float* __restrict__ emb,
                              float* __restrict__ feat, ushort_t* __restrict__ feat_bf) {
    int i = blockIdx.x * blockDim.x + threadIdx.x;  // over N*32 float4s
    int n = i >> 5, c = i & 31;
    int id = ids[n];
    float4 v = ((const float4*)emb)[(size_t)id * 32 + c];
    ((float4*)feat)[(size_t)n * 32 + c] = v;
    ushort4 b;
    b.x = f2bf(v.x); b.y = f2bf(v.y); b.z = f2bf(v.z); b.w = f2bf(v.w);
    ((ushort4*)feat_bf)[(size_t)n * 32 + c] = b;
}

__global__ void maxpool_kernel(const float* __restrict__ x, float* __restrict__ pools, int col_off) {
    int b = blockIdx.x, chunk = blockIdx.y, d = threadIdx.x;
    int i0 = chunk * 125, i1 = i0 + 125;
    float mx = -FLT_MAX;
    for (int i = i0; i < i1; ++i)
        mx = fmaxf(mx, x[((size_t)(b * NPGc + i)) * Dd + d]);
    atomicMaxF(&pools[b * (3 * Dd) + col_off + d], mx);
}

// Build Wt [1536][128] bf16 (fused W_src|W_dst|W_res transposed), Wt_gc [128][128] bf16, bias_f[1536]
__global__ void prep_kernel(const float* __restrict__ W_src, const float* __restrict__ W_dst,
                            const float* __restrict__ W_res, const float* __restrict__ W_gc,
                            const float* __restrict__ b_src, const float* __restrict__ b_dst,
                            const float* __restrict__ b_res,
                            ushort_t* __restrict__ Wt, ushort_t* __restrict__ Wt_gc,
                            float* __restrict__ bias_f) {
    int i = blockIdx.x * blockDim.x + threadIdx.x;
    if (i < WNf * 128) {
        int c = i >> 7, k = i & 127;
        float v = (c < 512) ? W_src[k * 512 + c]
                : (c < 1024) ? W_dst[k * 512 + (c - 512)]
                             : W_res[k * 512 + (c - 1024)];
        Wt[i] = f2bf(v);
    } else if (i < WNf * 128 + 128 * 128) {
        int j = i - WNf * 128;
        int c = j >> 7, k = j & 127;
        Wt_gc[j] = f2bf(W_gc[k * 128 + c]);
    }
    if (i < WNf)
        bias_f[i] = (i < 512) ? b_src[i] : (i < 1024) ? b_dst[i - 512] : b_res[i - 1024];
}

// ---- LDS-free MFMA GEMM: C[n,c] = act( A[n,:] @ Wt[c,:] + bias[c] ) ----
// A [n_rows][128] bf16, Wt [WN][128] bf16 (pre-transposed). Tile 128 rows x 64 cols.
// Fragments loaded DIRECTLY from global (16 B/lane, 64 B/row segments): no LDS,
// no barriers, no bank conflicts. Bijective XCD swizzle keeps each XCD's A-rows
// in its own L2 (col index fastest within the XCD's contiguous lin range).
__global__ __launch_bounds__(256) void mfma_gemm_kernel(
    const ushort_t* __restrict__ A, const ushort_t* __restrict__ Wt,
    const float* __restrict__ bias, ushort_t* __restrict__ Ob, float* __restrict__ Of,
    int n_rows, int WN, int do_leak, int ncb)
{
    int nwg = gridDim.x;
    int q = nwg >> 3, r = nwg & 7;
    int xcd = blockIdx.x & 7, idx = blockIdx.x >> 3;
    int lin = (xcd < r ? xcd * (q + 1) : r * (q + 1) + (xcd - r) * q) + idx;
    int col0 = (lin % ncb) * 64;
    int row0 = (lin / ncb) * 128;

    int wv = threadIdx.x >> 6, lane = threadIdx.x & 63;
    int wr = wv >> 1, wc = wv & 1;       // wave tile: rows wr*64, cols wc*32
    int lrow = lane & 15, kg = lane >> 4;

    const ushort_t* ap = A  + ((size_t)(row0 + wr * 64 + lrow) * 128 + kg * 8);
    const ushort_t* bp = Wt + ((size_t)(col0 + wc * 32 + lrow) * 128 + kg * 8);

    f32x4 acc[4][2] = {};
    #pragma unroll
    for (int ks = 0; ks < 4; ++ks) {
        bf16x8 av[4], bv[2];
        #pragma unroll
        for (int fi = 0; fi < 4; ++fi)
            av[fi] = *(const bf16x8*)(ap + fi * 16 * 128 + ks * 32);
        #pragma unroll
        for (int fj = 0; fj < 2; ++fj)
            bv[fj] = *(const bf16x8*)(bp + fj * 16 * 128 + ks * 32);
        #pragma unroll
        for (int fi = 0; fi < 4; ++fi)
            #pragma unroll
            for (int fj = 0; fj < 2; ++fj)
                acc[fi][fj] = __builtin_amdgcn_mfma_f32_16x16x32_bf16(av[fi], bv[fj], acc[fi][fj], 0, 0, 0);
    }

    // epilogue: D lane mapping col = lane&15, row = (lane>>4)*4 + j
    #pragma unroll
    for (int fj = 0; fj < 2; ++fj) {
        int col = col0 + wc * 32 + fj * 16 + lrow;
        float bval = bias[col];
        #pragma unroll
        for (int fi = 0; fi < 4; ++fi) {
            #pragma unroll
            for (int j = 0; j < 4; ++j) {
                int grow = row0 + wr * 64 + fi * 16 + kg * 4 + j;
                if (grow >= n_rows) continue;
                float v = acc[fi][fj][j] + bval;
                if (do_leak) v = v >= 0.0f ? v : 0.01f * v;
                if (Ob) Ob[(size_t)grow * WN + col] = f2bf(v);
                else    Of[(size_t)grow * WN + col] = v;
            }
        }
    }
}

// ---- CSR build ----
__global__ void degree2_kernel(const int* __restrict__ src, const int* __restrict__ dst,
                               int* __restrict__ din_i, float* __restrict__ dout) {
    int e = blockIdx.x * blockDim.x + threadIdx.x;
    if (e >= Ee) return;
    atomicAdd(&din_i[dst[e]], 1);
    atomicAdd(&dout[src[e]], 1.0f);
}

// two-level scan: per-chunk reduce -> serial scan of 49 partials -> per-chunk scan
__global__ __launch_bounds__(256) void scan_reduce_kernel(const int* __restrict__ din_i,
                                                          int* __restrict__ partials) {
    int b = blockIdx.x, t = threadIdx.x;
    int base = b * 1024 + t * 4;
    int s = 0;
    #pragma unroll
    for (int j = 0; j < 4; ++j) { int i = base + j; if (i < Nn) s += din_i[i]; }
    #pragma unroll
    for (int off = 32; off > 0; off >>= 1) s += __shfl_xor(s, off);
    __shared__ int wsum[4];
    if ((t & 63) == 0) wsum[t >> 6] = s;
    __syncthreads();
    if (t == 0) partials[b] = wsum[0] + wsum[1] + wsum[2] + wsum[3];
}

__global__ void scan_mid_kernel(int* __restrict__ partials, int* __restrict__ row_start) {
    if (threadIdx.x == 0) {
        int acc = 0;
        for (int i = 0; i < NCHUNK; ++i) { int v = partials[i]; partials[i] = acc; acc += v; }
        row_start[Nn] = acc;
    }
}

__global__ __launch_bounds__(256) void scan_final_kernel(const int* __restrict__ din_i,
                                                         const int* __restrict__ partials,
                                                         int* __restrict__ row_start,
                                                         float* __restrict__ din_f) {
    int b = blockIdx.x, t = threadIdx.x;
    int base = b * 1024 + t * 4;
    int v[4]; int s = 0;
    #pragma unroll
    for (int j = 0; j < 4; ++j) {
        v[j] = (base + j < Nn) ? din_i[base + j] : 0;
        s += v[j];
    }
    __shared__ int buf[256];
    buf[t] = s;
    __syncthreads();
    #pragma unroll
    for (int off = 1; off < 256; off <<= 1) {
        int x = (t >= off) ? buf[t - off] : 0;
        __syncthreads();
        buf[t] += x;
        __syncthreads();
    }
    int excl = buf[t] - s + partials[b];
    #pragma unroll
    for (int j = 0; j < 4; ++j) {
        if (base + j < Nn) {
            row_start[base + j] = excl;
            din_f[base + j] = (float)v[j];
            excl += v[j];
        }
    }
}

__global__ void scatter_kernel(const int* __restrict__ src, const int* __restrict__ dst,
                               const int* __restrict__ row_start, int* __restrict__ cursor,
                               int* __restrict__ csr_src) {
    int e = blockIdx.x * blockDim.x + threadIdx.x;
    if (e >= Ee) return;
    int d = dst[e];
    int slot = row_start[d] + atomicAdd(&cursor[d], 1);
    csr_src[slot] = src[e];
}

// ---- fused GATv2: one wave per dst node, online softmax over in-edges ----
// h_all row: [hs(512) | hd(512) | rres(512)] bf16. lane l owns flat cols [8l,8l+8), head = l>>4
__global__ __launch_bounds__(256) void gat_fused_kernel(
    const ushort_t* __restrict__ h_all, const float* __restrict__ attn,
    const int* __restrict__ row_start, const int* __restrict__ csr_src,
    float* __restrict__ res)
{
    int d = (blockIdx.x * 256 + threadIdx.x) >> 6;
    int lane = threadIdx.x & 63;
    if (d >= Nn) return;
    int e0 = row_start[d], e1 = row_start[d + 1];

    float hdv[8], atv[8];
    {
        uint4 hr = *(const uint4*)(h_all + (size_t)d * WNf + 512 + lane * 8);
        bf2x2(hr.x, hdv[0], hdv[1]); bf2x2(hr.y, hdv[2], hdv[3]);
        bf2x2(hr.z, hdv[4], hdv[5]); bf2x2(hr.w, hdv[6], hdv[7]);
        float4 a0 = *(const float4*)(attn + lane * 8);
        float4 a1 = *(const float4*)(attn + lane * 8 + 4);
        atv[0] = a0.x; atv[1] = a0.y; atv[2] = a0.z; atv[3] = a0.w;
        atv[4] = a1.x; atv[5] = a1.y; atv[6] = a1.z; atv[7] = a1.w;
    }

    float m = -FLT_MAX, denom = 0.0f;
    float acc[8] = {};

    int s = (e0 < e1) ? csr_src[e0] : 0;
    for (int e = e0; e < e1; ++e) {
        int s_next = (e + 1 < e1) ? csr_src[e + 1] : 0;
        uint4 raw = *(const uint4*)(h_all + (size_t)s * WNf + lane * 8);
        float hsv[8];
        bf2x2(raw.x, hsv[0], hsv[1]); bf2x2(raw.y, hsv[2], hsv[3]);
        bf2x2(raw.z, hsv[4], hsv[5]); bf2x2(raw.w, hsv[6], hsv[7]);
        float p = 0.0f;
        #pragma unroll
        for (int j = 0; j < 8; ++j) {
            float x = hsv[j] + hdv[j];
            x = x >= 0.0f ? x : 0.2f * x;
            p = fmaf(x, atv[j], p);
        }
        p += __shfl_xor(p, 1); p += __shfl_xor(p, 2);
        p += __shfl_xor(p, 4); p += __shfl_xor(p, 8);
        float mn = fmaxf(m, p);
        float corr = expf(m - mn);
        float ex = expf(p - mn);
        denom = denom * corr + ex;
        #pragma unroll
        for (int j = 0; j < 8; ++j) acc[j] = fmaf(acc[j], corr, hsv[j] * ex);
        m = mn;
        s = s_next;
    }

    float inv = (e1 > e0) ? 1.0f / denom : 0.0f;
    float rv[8];
    {
        uint4 rr = *(const uint4*)(h_all + (size_t)d * WNf + 1024 + lane * 8);
        bf2x2(rr.x, rv[0], rv[1]); bf2x2(rr.y, rv[2], rv[3]);
        bf2x2(rr.z, rv[4], rv[5]); bf2x2(rr.w, rv[6], rv[7]);
    }
    float t[8];
    #pragma unroll
    for (int j = 0; j < 8; ++j) {
        float v = fmaf(acc[j], inv, rv[j]);
        t[j] = v >= 0.0f ? v : 0.01f * v;
    }
    #pragma unroll
    for (int j = 0; j < 8; ++j) {
        t[j] += __shfl_xor(t[j], 16);
        t[j] += __shfl_xor(t[j], 32);
    }
    if (lane < 16) {
        float o0[4] = {0.25f * t[0], 0.25f * t[1], 0.25f * t[2], 0.25f * t[3]};
        float o1[4] = {0.25f * t[4], 0.25f * t[5], 0.25f * t[6], 0.25f * t[7]};
        *(float4*)(res + (size_t)d * Dd + lane * 8)     = *(float4*)o0;
        *(float4*)(res + (size_t)d * Dd + lane * 8 + 4) = *(float4*)o1;
    }
}

// ---- GraphConv aggregate via CSR; epilogue applies rsqrt(din) and emits bf16 ----
__global__ __launch_bounds__(256) void gc_gather_kernel(
    const float* __restrict__ res, const int* __restrict__ row_start,
    const int* __restrict__ csr_src, const float* __restrict__ dout,
    const float* __restrict__ din, ushort_t* __restrict__ agg_bf)
{
    int d = (blockIdx.x * 256 + threadIdx.x) >> 6;
    int lane = threadIdx.x & 63;
    if (d >= Nn) return;
    int e0 = row_start[d], e1 = row_start[d + 1];
    float ax = 0.0f, ay = 0.0f;
    int s = (e0 < e1) ? csr_src[e0] : 0;
    for (int e = e0; e < e1; ++e) {
        int s_next = (e + 1 < e1) ? csr_src[e + 1] : 0;
        float sc = 1.0f / sqrtf(fmaxf(dout[s], 1.0f));
        float2 v = ((const float2*)(res + (size_t)s * Dd))[lane];
        ax = fmaf(v.x, sc, ax);
        ay = fmaf(v.y, sc, ay);
        s = s_next;
    }
    float scd = 1.0f / sqrtf(fmaxf(din[d], 1.0f));
    ushort2 o;
    o.x = f2bf(ax * scd);
    o.y = f2bf(ay * scd);
    ((ushort2*)(agg_bf + (size_t)d * Dd))[lane] = o;
}

__global__ void final_kernel(const float* __restrict__ pools, const float* __restrict__ W_mlp,
                             const float* __restrict__ b_mlp, float* __restrict__ out) {
    int b = blockIdx.x, lane = threadIdx.x;
    float s = 0.0f;
    for (int j = lane; j < 3 * Dd; j += 64)
        s += fmaxf(pools[b * (3 * Dd) + j], 0.0f) * W_mlp[j];
    #pragma unroll
    for (int off = 32; off > 0; off >>= 1) s += __shfl_xor(s, off);
    if (lane == 0) out[b] = s + b_mlp[0];
}

extern "C" void kernel_launch(void* const* d_in, const int* in_sizes, int n_in,
                              void* d_out, int out_size, void* d_ws, size_t ws_size,
                              hipStream_t stream) {
    const int*   node_ids = (const int*)d_in[0];
    const int*   src      = (const int*)d_in[1];
    const int*   dst      = (const int*)d_in[2];
    const float* emb      = (const float*)d_in[3];
    const float* W_src    = (const float*)d_in[4];
    const float* b_src    = (const float*)d_in[5];
    const float* W_dst    = (const float*)d_in[6];
    const float* b_dst    = (const float*)d_in[7];
    const float* attn     = (const float*)d_in[8];
    const float* W_res    = (const float*)d_in[9];
    const float* b_res    = (const float*)d_in[10];
    const float* W_gc     = (const float*)d_in[11];
    const float* b_gc     = (const float*)d_in[12];
    const float* W_mlp    = (const float*)d_in[13];
    const float* b_mlp    = (const float*)d_in[14];
    float* out = (float*)d_out;

    char* w = (char*)d_ws;
    size_t off = 0;
    float*    feat    = (float*)(w + off);    off += (size_t)Nn * Dd * 4;        // 25.6 MB
    ushort_t* feat_bf = (ushort_t*)(w + off); off += (size_t)Nn * Dd * 2;        // 12.8 MB
    ushort_t* h_all   = (ushort_t*)(w + off); off += (size_t)Nn * WNf * 2;       // 153.6 MB
    ushort_t* Wt      = (ushort_t*)(w + off); off += (size_t)WNf * 128 * 2;
    ushort_t* Wt_gc   = (ushort_t*)(w + off); off += (size_t)128 * 128 * 2;
    float*    bias_f  = (float*)(w + off);    off += (size_t)WNf * 4;
    int*      csr_src = (int*)(w + off);      off += (size_t)Ee * 4;
    int*      row_st  = (int*)(w + off);      off += ((size_t)Nn + 4) * 4;
    int*      cursor  = (int*)(w + off);      off += (size_t)Nn * 4;
    int*      din_i   = (int*)(w + off);      off += (size_t)Nn * 4;
    float*    din_f   = (float*)(w + off);    off += (size_t)Nn * 4;
    float*    dout_f  = (float*)(w + off);    off += (size_t)Nn * 4;
    int*      partials= (int*)(w + off);      off += 64 * 4;
    float*    pools   = (float*)(w + off);    off += (size_t)Bg * 3 * Dd * 4;

    float*    res    = feat;                                  // feat dead after fused GEMM
    ushort_t* agg_bf = h_all;                                 // h_all dead after gat_fused
    float*    res2   = (float*)(w + (size_t)Nn * Dd * 6 + (size_t)Nn * Dd * 2);  // inside h_all, past agg_bf

    init_kernel<<<(Nn + 255) / 256, 256, 0, stream>>>(din_i, dout_f, cursor, pools);
    gather_kernel<<<(Nn * 32) / 256, 256, 0, stream>>>(node_ids, emb, feat, feat_bf);
    maxpool_kernel<<<dim3(Bg, 50), Dd, 0, stream>>>(feat, pools, 0);

    prep_kernel<<<(WNf * 128 + 128 * 128 + 255) / 256, 256, 0, stream>>>(
        W_src, W_dst, W_res, W_gc, b_src, b_dst, b_res, Wt, Wt_gc, bias_f);

    // CSR build
    degree2_kernel<<<(Ee + 255) / 256, 256, 0, stream>>>(src, dst, din_i, dout_f);
    scan_reduce_kernel<<<NCHUNK, 256, 0, stream>>>(din_i, partials);
    scan_mid_kernel<<<1, 64, 0, stream>>>(partials, row_st);
    scan_final_kernel<<<NCHUNK, 256, 0, stream>>>(din_i, partials, row_st, din_f);
    scatter_kernel<<<(Ee + 255) / 256, 256, 0, stream>>>(src, dst, row_st, cursor, csr_src);

    // fused hs|hd|rres GEMM via MFMA (LDS-free), 9384 blocks = 24 col x 391 row tiles
    mfma_gemm_kernel<<<24 * 391, 256, 0, stream>>>(
        feat_bf, Wt, bias_f, h_all, nullptr, Nn, WNf, 0, 24);

    gat_fused_kernel<<<(Nn * 64) / 256, 256, 0, stream>>>(h_all, attn, row_st, csr_src, res);
    maxpool_kernel<<<dim3(Bg, 50), Dd, 0, stream>>>(res, pools, Dd);

    gc_gather_kernel<<<(Nn * 64) / 256, 256, 0, stream>>>(res, row_st, csr_src, dout_f, din_f, agg_bf);
    mfma_gemm_kernel<<<2 * 391, 256, 0, stream>>>(
        agg_bf, Wt_gc, b_gc, nullptr, res2, Nn, Dd, 1, 2);
    maxpool_kernel<<<dim3(Bg, 50), Dd, 0, stream>>>(res2, pools, 2 * Dd);

    final_kernel<<<Bg, 64, 0, stream>>>(pools, W_mlp, b_mlp, out);
}

// Round 9
// 413.252 us; speedup vs baseline: 5.7394x; 1.1144x over previous
//
#include <hip/hip_runtime.h>
#include <float.h>
#include <math.h>

#define Bg   8
#define NPGc 6250
#define Hh   4
#define Dd   128
#define Nn   50000
#define Ee   400000
#define HDd  512
#define WNf  1536   // fused hs|hd|rres width
#define NCHUNK 49   // ceil(50000/1024)

typedef unsigned short ushort_t;
typedef __attribute__((ext_vector_type(8))) short bf16x8;
typedef __attribute__((ext_vector_type(4))) float f32x4;

__device__ __forceinline__ void atomicMaxF(float* addr, float val) {
    if (val >= 0.0f) atomicMax((int*)addr, __float_as_int(val));
    else             atomicMin((unsigned int*)addr, __float_as_uint(val));
}

__device__ __forceinline__ ushort_t f2bf(float x) {
    unsigned u = __float_as_uint(x);
    unsigned r = (u + 0x7FFFu + ((u >> 16) & 1u)) >> 16;   // RNE
    return (ushort_t)r;
}

__device__ __forceinline__ void bf2x2(unsigned u, float& lo, float& hi) {
    lo = __uint_as_float(u << 16);
    hi = __uint_as_float(u & 0xFFFF0000u);
}

// async global->LDS, 16 B per lane; lds dest must be wave-uniform base (+lane*16 implicit)
__device__ __forceinline__ void gload16(const void* g, void* l) {
    __builtin_amdgcn_global_load_lds(
        (const __attribute__((address_space(1))) unsigned int*)g,
        (__attribute__((address_space(3))) unsigned int*)l, 16, 0, 0);
}

__global__ void init_kernel(int* din_i, float* dout, int* cursor, float* pools) {
    int i = blockIdx.x * blockDim.x + threadIdx.x;
    if (i < Nn) { din_i[i] = 0; dout[i] = 0.0f; cursor[i] = 0; }
    if (i < Bg * 3 * Dd) pools[i] = -FLT_MAX;
}

__global__ void gather_kernel(const int* __restrict__ ids, const float* __restrict__ emb,
                              float* __restrict__ feat, ushort_t* __restrict__ feat_bf) {
    int i = blockIdx.x * blockDim.x + threadIdx.x;  // over N*32 float4s
    int n = i >> 5, c = i & 31;
    int id = ids[n];
    float4 v = ((const float4*)emb)[(size_t)id * 32 + c];
    ((float4*)feat)[(size_t)n * 32 + c] = v;
    ushort4 b;
    b.x = f2bf(v.x); b.y = f2bf(v.y); b.z = f2bf(v.z); b.w = f2bf(v.w);
    ((ushort4*)feat_bf)[(size_t)n * 32 + c] = b;
}

__global__ void maxpool_kernel(const float* __restrict__ x, float* __restrict__ pools, int col_off) {
    int b = blockIdx.x, chunk = blockIdx.y, d = threadIdx.x;
    int i0 = chunk * 125, i1 = i0 + 125;
    float mx = -FLT_MAX;
    for (int i = i0; i < i1; ++i)
        mx = fmaxf(mx, x[((size_t)(b * NPGc + i)) * Dd + d]);
    atomicMaxF(&pools[b * (3 * Dd) + col_off + d], mx);
}

// Build Wt [1536][128] bf16 (fused W_src|W_dst|W_res transposed), Wt_gc [128][128] bf16, bias_f[1536]
__global__ void prep_kernel(const float* __restrict__ W_src, const float* __restrict__ W_dst,
                            const float* __restrict__ W_res, const float* __restrict__ W_gc,
                            const float* __restrict__ b_src, const float* __restrict__ b_dst,
                            const float* __restrict__ b_res,
                            ushort_t* __restrict__ Wt, ushort_t* __restrict__ Wt_gc,
                            float* __restrict__ bias_f) {
    int i = blockIdx.x * blockDim.x + threadIdx.x;
    if (i < WNf * 128) {
        int c = i >> 7, k = i & 127;
        float v = (c < 512) ? W_src[k * 512 + c]
                : (c < 1024) ? W_dst[k * 512 + (c - 512)]
                             : W_res[k * 512 + (c - 1024)];
        Wt[i] = f2bf(v);
    } else if (i < WNf * 128 + 128 * 128) {
        int j = i - WNf * 128;
        int c = j >> 7, k = j & 127;
        Wt_gc[j] = f2bf(W_gc[k * 128 + c]);
    }
    if (i < WNf)
        bias_f[i] = (i < 512) ? b_src[i] : (i < 1024) ? b_dst[i - 512] : b_res[i - 1024];
}

// ---- Pipelined MFMA GEMM: C[n,c] = act( A[n,:] @ Wt[c,:] + bias[c] ) ----
// Block = 64 A-rows x full width; A fragments live in registers (K=128, one-time load).
// W 64-col tiles double-buffered in LDS via global_load_lds with pre-swizzled source
// (byte ^= (row&7)<<4) so ds_read_b128 fragment reads are bank-conflict-free.
// Operand-swapped MFMA => each lane holds 4 consecutive C-cols => vectorized stores.
// 4 waves: wave w owns cols [w*16, w*16+16) of each 64-col tile, all 64 rows.
__global__ __launch_bounds__(256) void mfma_gemm_kernel(
    const ushort_t* __restrict__ A, const ushort_t* __restrict__ Wt,
    const float* __restrict__ bias, ushort_t* __restrict__ Ob, float* __restrict__ Of,
    int n_rows, int WN, int do_leak)
{
    __shared__ char Ws[2][16384] __attribute__((aligned(16)));
    int row0 = blockIdx.x * 64;
    int tid = threadIdx.x;
    int w = tid >> 6, lane = tid & 63;
    int lrow = lane & 15, kg = lane >> 4;
    int NC = WN >> 6;   // 64-col tiles

    // one-time A fragments: av[fi][ks], rows row0+fi*16+lrow, k = ks*32+kg*8
    bf16x8 av[4][4];
    {
        const ushort_t* ap = A + (size_t)(row0 + lrow) * 128 + kg * 8;
        #pragma unroll
        for (int fi = 0; fi < 4; ++fi)
            #pragma unroll
            for (int ks = 0; ks < 4; ++ks)
                av[fi][ks] = *(const bf16x8*)(ap + (size_t)fi * 16 * 128 + ks * 32);
    }

    // stage W col-tile ct into buf: tile = [64 wrows][256 B], swizzled source
    auto stage = [&](int ct, int buf) {
        #pragma unroll
        for (int i = 0; i < 4; ++i) {
            int s = i * 4096 + w * 1024 + lane * 16;  // byte slot (linear LDS order)
            int r = s >> 8;                            // W row within tile
            int p = (s >> 4) & 15;                     // 16B unit within row
            int sbyte = (p * 16) ^ ((r & 7) << 4);     // pre-swizzled source byte
            const ushort_t* g = Wt + (size_t)(ct * 64 + r) * 128 + (sbyte >> 1);
            gload16(g, &Ws[buf][i * 4096 + w * 1024]);
        }
    };

    stage(0, 0);
    __syncthreads();

    for (int ct = 0; ct < NC; ++ct) {
        int cur = ct & 1;
        if (ct + 1 < NC) stage(ct + 1, cur ^ 1);

        // W fragments for this wave's 16-col slice: wrow = w*16+lrow
        bf16x8 wv[4];
        {
            const char* lb = Ws[cur] + (w * 16 + lrow) * 256;
            #pragma unroll
            for (int ks = 0; ks < 4; ++ks) {
                int byte = (kg * 16 + ks * 64) ^ ((lrow & 7) << 4);
                wv[ks] = *(const bf16x8*)(lb + byte);
            }
        }

        f32x4 acc[4] = {};
        #pragma unroll
        for (int ks = 0; ks < 4; ++ks)
            #pragma unroll
            for (int fi = 0; fi < 4; ++fi)
                acc[fi] = __builtin_amdgcn_mfma_f32_16x16x32_bf16(wv[ks], av[fi][ks], acc[fi], 0, 0, 0);

        // D (swapped): lane (kg,lrow) holds C rows row0+fi*16+lrow, cols ct*64+w*16+kg*4+{0..3}
        int colb = ct * 64 + w * 16 + kg * 4;
        float4 bv4 = *(const float4*)(bias + colb);
        #pragma unroll
        for (int fi = 0; fi < 4; ++fi) {
            int grow = row0 + fi * 16 + lrow;
            if (grow < n_rows) {
                float o[4];
                #pragma unroll
                for (int j = 0; j < 4; ++j) {
                    float v = acc[fi][j] + ((const float*)&bv4)[j];
                    if (do_leak) v = v >= 0.0f ? v : 0.01f * v;
                    o[j] = v;
                }
                if (Ob) {
                    ushort4 ob;
                    ob.x = f2bf(o[0]); ob.y = f2bf(o[1]); ob.z = f2bf(o[2]); ob.w = f2bf(o[3]);
                    *(ushort4*)(Ob + (size_t)grow * WN + colb) = ob;
                } else {
                    *(float4*)(Of + (size_t)grow * WN + colb) = *(float4*)o;
                }
            }
        }
        __syncthreads();
    }
}

// ---- CSR build ----
__global__ void degree2_kernel(const int* __restrict__ src, const int* __restrict__ dst,
                               int* __restrict__ din_i, float* __restrict__ dout) {
    int e = blockIdx.x * blockDim.x + threadIdx.x;
    if (e >= Ee) return;
    atomicAdd(&din_i[dst[e]], 1);
    atomicAdd(&dout[src[e]], 1.0f);
}

// two-level scan: per-chunk reduce -> serial scan of 49 partials -> per-chunk scan
__global__ __launch_bounds__(256) void scan_reduce_kernel(const int* __restrict__ din_i,
                                                          int* __restrict__ partials) {
    int b = blockIdx.x, t = threadIdx.x;
    int base = b * 1024 + t * 4;
    int s = 0;
    #pragma unroll
    for (int j = 0; j < 4; ++j) { int i = base + j; if (i < Nn) s += din_i[i]; }
    #pragma unroll
    for (int off = 32; off > 0; off >>= 1) s += __shfl_xor(s, off);
    __shared__ int wsum[4];
    if ((t & 63) == 0) wsum[t >> 6] = s;
    __syncthreads();
    if (t == 0) partials[b] = wsum[0] + wsum[1] + wsum[2] + wsum[3];
}

__global__ void scan_mid_kernel(int* __restrict__ partials, int* __restrict__ row_start) {
    if (threadIdx.x == 0) {
        int acc = 0;
        for (int i = 0; i < NCHUNK; ++i) { int v = partials[i]; partials[i] = acc; acc += v; }
        row_start[Nn] = acc;
    }
}

__global__ __launch_bounds__(256) void scan_final_kernel(const int* __restrict__ din_i,
                                                         const int* __restrict__ partials,
                                                         int* __restrict__ row_start,
                                                         float* __restrict__ din_f) {
    int b = blockIdx.x, t = threadIdx.x;
    int base = b * 1024 + t * 4;
    int v[4]; int s = 0;
    #pragma unroll
    for (int j = 0; j < 4; ++j) {
        v[j] = (base + j < Nn) ? din_i[base + j] : 0;
        s += v[j];
    }
    __shared__ int buf[256];
    buf[t] = s;
    __syncthreads();
    #pragma unroll
    for (int off = 1; off < 256; off <<= 1) {
        int x = (t >= off) ? buf[t - off] : 0;
        __syncthreads();
        buf[t] += x;
        __syncthreads();
    }
    int excl = buf[t] - s + partials[b];
    #pragma unroll
    for (int j = 0; j < 4; ++j) {
        if (base + j < Nn) {
            row_start[base + j] = excl;
            din_f[base + j] = (float)v[j];
            excl += v[j];
        }
    }
}

__global__ void scatter_kernel(const int* __restrict__ src, const int* __restrict__ dst,
                               const int* __restrict__ row_start, int* __restrict__ cursor,
                               int* __restrict__ csr_src) {
    int e = blockIdx.x * blockDim.x + threadIdx.x;
    if (e >= Ee) return;
    int d = dst[e];
    int slot = row_start[d] + atomicAdd(&cursor[d], 1);
    csr_src[slot] = src[e];
}

// ---- fused GATv2: one wave per dst node, online softmax over in-edges ----
// h_all row: [hs(512) | hd(512) | rres(512)] bf16. lane l owns flat cols [8l,8l+8), head = l>>4
__global__ __launch_bounds__(256) void gat_fused_kernel(
    const ushort_t* __restrict__ h_all, const float* __restrict__ attn,
    const int* __restrict__ row_start, const int* __restrict__ csr_src,
    float* __restrict__ res)
{
    int d = (blockIdx.x * 256 + threadIdx.x) >> 6;
    int lane = threadIdx.x & 63;
    if (d >= Nn) return;
    int e0 = row_start[d], e1 = row_start[d + 1];

    float hdv[8], atv[8];
    {
        uint4 hr = *(const uint4*)(h_all + (size_t)d * WNf + 512 + lane * 8);
        bf2x2(hr.x, hdv[0], hdv[1]); bf2x2(hr.y, hdv[2], hdv[3]);
        bf2x2(hr.z, hdv[4], hdv[5]); bf2x2(hr.w, hdv[6], hdv[7]);
        float4 a0 = *(const float4*)(attn + lane * 8);
        float4 a1 = *(const float4*)(attn + lane * 8 + 4);
        atv[0] = a0.x; atv[1] = a0.y; atv[2] = a0.z; atv[3] = a0.w;
        atv[4] = a1.x; atv[5] = a1.y; atv[6] = a1.z; atv[7] = a1.w;
    }

    float m = -FLT_MAX, denom = 0.0f;
    float acc[8] = {};

    int s = (e0 < e1) ? csr_src[e0] : 0;
    for (int e = e0; e < e1; ++e) {
        int s_next = (e + 1 < e1) ? csr_src[e + 1] : 0;
        uint4 raw = *(const uint4*)(h_all + (size_t)s * WNf + lane * 8);
        float hsv[8];
        bf2x2(raw.x, hsv[0], hsv[1]); bf2x2(raw.y, hsv[2], hsv[3]);
        bf2x2(raw.z, hsv[4], hsv[5]); bf2x2(raw.w, hsv[6], hsv[7]);
        float p = 0.0f;
        #pragma unroll
        for (int j = 0; j < 8; ++j) {
            float x = hsv[j] + hdv[j];
            x = x >= 0.0f ? x : 0.2f * x;
            p = fmaf(x, atv[j], p);
        }
        p += __shfl_xor(p, 1); p += __shfl_xor(p, 2);
        p += __shfl_xor(p, 4); p += __shfl_xor(p, 8);
        float mn = fmaxf(m, p);
        float corr = expf(m - mn);
        float ex = expf(p - mn);
        denom = denom * corr + ex;
        #pragma unroll
        for (int j = 0; j < 8; ++j) acc[j] = fmaf(acc[j], corr, hsv[j] * ex);
        m = mn;
        s = s_next;
    }

    float inv = (e1 > e0) ? 1.0f / denom : 0.0f;
    float rv[8];
    {
        uint4 rr = *(const uint4*)(h_all + (size_t)d * WNf + 1024 + lane * 8);
        bf2x2(rr.x, rv[0], rv[1]); bf2x2(rr.y, rv[2], rv[3]);
        bf2x2(rr.z, rv[4], rv[5]); bf2x2(rr.w, rv[6], rv[7]);
    }
    float t[8];
    #pragma unroll
    for (int j = 0; j < 8; ++j) {
        float v = fmaf(acc[j], inv, rv[j]);
        t[j] = v >= 0.0f ? v : 0.01f * v;
    }
    #pragma unroll
    for (int j = 0; j < 8; ++j) {
        t[j] += __shfl_xor(t[j], 16);
        t[j] += __shfl_xor(t[j], 32);
    }
    if (lane < 16) {
        float o0[4] = {0.25f * t[0], 0.25f * t[1], 0.25f * t[2], 0.25f * t[3]};
        float o1[4] = {0.25f * t[4], 0.25f * t[5], 0.25f * t[6], 0.25f * t[7]};
        *(float4*)(res + (size_t)d * Dd + lane * 8)     = *(float4*)o0;
        *(float4*)(res + (size_t)d * Dd + lane * 8 + 4) = *(float4*)o1;
    }
}

// ---- GraphConv aggregate via CSR; epilogue applies rsqrt(din) and emits bf16 ----
__global__ __launch_bounds__(256) void gc_gather_kernel(
    const float* __restrict__ res, const int* __restrict__ row_start,
    const int* __restrict__ csr_src, const float* __restrict__ dout,
    const float* __restrict__ din, ushort_t* __restrict__ agg_bf)
{
    int d = (blockIdx.x * 256 + threadIdx.x) >> 6;
    int lane = threadIdx.x & 63;
    if (d >= Nn) return;
    int e0 = row_start[d], e1 = row_start[d + 1];
    float ax = 0.0f, ay = 0.0f;
    int s = (e0 < e1) ? csr_src[e0] : 0;
    for (int e = e0; e < e1; ++e) {
        int s_next = (e + 1 < e1) ? csr_src[e + 1] : 0;
        float sc = 1.0f / sqrtf(fmaxf(dout[s], 1.0f));
        float2 v = ((const float2*)(res + (size_t)s * Dd))[lane];
        ax = fmaf(v.x, sc, ax);
        ay = fmaf(v.y, sc, ay);
        s = s_next;
    }
    float scd = 1.0f / sqrtf(fmaxf(din[d], 1.0f));
    ushort2 o;
    o.x = f2bf(ax * scd);
    o.y = f2bf(ay * scd);
    ((ushort2*)(agg_bf + (size_t)d * Dd))[lane] = o;
}

__global__ void final_kernel(const float* __restrict__ pools, const float* __restrict__ W_mlp,
                             const float* __restrict__ b_mlp, float* __restrict__ out) {
    int b = blockIdx.x, lane = threadIdx.x;
    float s = 0.0f;
    for (int j = lane; j < 3 * Dd; j += 64)
        s += fmaxf(pools[b * (3 * Dd) + j], 0.0f) * W_mlp[j];
    #pragma unroll
    for (int off = 32; off > 0; off >>= 1) s += __shfl_xor(s, off);
    if (lane == 0) out[b] = s + b_mlp[0];
}

extern "C" void kernel_launch(void* const* d_in, const int* in_sizes, int n_in,
                              void* d_out, int out_size, void* d_ws, size_t ws_size,
                              hipStream_t stream) {
    const int*   node_ids = (const int*)d_in[0];
    const int*   src      = (const int*)d_in[1];
    const int*   dst      = (const int*)d_in[2];
    const float* emb      = (const float*)d_in[3];
    const float* W_src    = (const float*)d_in[4];
    const float* b_src    = (const float*)d_in[5];
    const float* W_dst    = (const float*)d_in[6];
    const float* b_dst    = (const float*)d_in[7];
    const float* attn     = (const float*)d_in[8];
    const float* W_res    = (const float*)d_in[9];
    const float* b_res    = (const float*)d_in[10];
    const float* W_gc     = (const float*)d_in[11];
    const float* b_gc     = (const float*)d_in[12];
    const float* W_mlp    = (const float*)d_in[13];
    const float* b_mlp    = (const float*)d_in[14];
    float* out = (float*)d_out;

    char* w = (char*)d_ws;
    size_t off = 0;
    float*    feat    = (float*)(w + off);    off += (size_t)Nn * Dd * 4;        // 25.6 MB
    ushort_t* feat_bf = (ushort_t*)(w + off); off += (size_t)(Nn + 64) * Dd * 2; // 12.8 MB (+pad rows)
    ushort_t* h_all   = (ushort_t*)(w + off); off += (size_t)Nn * WNf * 2;       // 153.6 MB
    ushort_t* Wt      = (ushort_t*)(w + off); off += (size_t)WNf * 128 * 2;
    ushort_t* Wt_gc   = (ushort_t*)(w + off); off += (size_t)128 * 128 * 2;
    float*    bias_f  = (float*)(w + off);    off += (size_t)WNf * 4;
    int*      csr_src = (int*)(w + off);      off += (size_t)Ee * 4;
    int*      row_st  = (int*)(w + off);      off += ((size_t)Nn + 4) * 4;
    int*      cursor  = (int*)(w + off);      off += (size_t)Nn * 4;
    int*      din_i   = (int*)(w + off);      off += (size_t)Nn * 4;
    float*    din_f   = (float*)(w + off);    off += (size_t)Nn * 4;
    float*    dout_f  = (float*)(w + off);    off += (size_t)Nn * 4;
    int*      partials= (int*)(w + off);      off += 64 * 4;
    float*    pools   = (float*)(w + off);    off += (size_t)Bg * 3 * Dd * 4;

    float*    res    = feat;                                  // feat dead after fused GEMM
    ushort_t* agg_bf = h_all;                                 // h_all dead after gat_fused
    float*    res2   = (float*)(w + (size_t)Nn * Dd * 6 + (size_t)(Nn + 64) * Dd * 2);  // inside h_all, past agg_bf

    init_kernel<<<(Nn + 255) / 256, 256, 0, stream>>>(din_i, dout_f, cursor, pools);
    gather_kernel<<<(Nn * 32) / 256, 256, 0, stream>>>(node_ids, emb, feat, feat_bf);
    maxpool_kernel<<<dim3(Bg, 50), Dd, 0, stream>>>(feat, pools, 0);

    prep_kernel<<<(WNf * 128 + 128 * 128 + 255) / 256, 256, 0, stream>>>(
        W_src, W_dst, W_res, W_gc, b_src, b_dst, b_res, Wt, Wt_gc, bias_f);

    // CSR build
    degree2_kernel<<<(Ee + 255) / 256, 256, 0, stream>>>(src, dst, din_i, dout_f);
    scan_reduce_kernel<<<NCHUNK, 256, 0, stream>>>(din_i, partials);
    scan_mid_kernel<<<1, 64, 0, stream>>>(partials, row_st);
    scan_final_kernel<<<NCHUNK, 256, 0, stream>>>(din_i, partials, row_st, din_f);
    scatter_kernel<<<(Ee + 255) / 256, 256, 0, stream>>>(src, dst, row_st, cursor, csr_src);

    // fused hs|hd|rres GEMM via pipelined MFMA: 782 row-blocks of 64
    mfma_gemm_kernel<<<(Nn + 63) / 64, 256, 0, stream>>>(
        feat_bf, Wt, bias_f, h_all, nullptr, Nn, WNf, 0);

    gat_fused_kernel<<<(Nn * 64) / 256, 256, 0, stream>>>(h_all, attn, row_st, csr_src, res);
    maxpool_kernel<<<dim3(Bg, 50), Dd, 0, stream>>>(res, pools, Dd);

    gc_gather_kernel<<<(Nn * 64) / 256, 256, 0, stream>>>(res, row_st, csr_src, dout_f, din_f, agg_bf);
    mfma_gemm_kernel<<<(Nn + 63) / 64, 256, 0, stream>>>(
        agg_bf, Wt_gc, b_gc, nullptr, res2, Nn, Dd, 1);
    maxpool_kernel<<<dim3(Bg, 50), Dd, 0, stream>>>(res2, pools, 2 * Dd);

    final_kernel<<<Bg, 64, 0, stream>>>(pools, W_mlp, b_mlp, out);
}

// Round 10
// 403.655 us; speedup vs baseline: 5.8758x; 1.0238x over previous
//
#include <hip/hip_runtime.h>
#include <float.h>
#include <math.h>

#define Bg   8
#define NPGc 6250
#define Hh   4
#define Dd   128
#define Nn   50000
#define Ee   400000
#define HDd  512
#define WNf  1536   // fused hs|hd|rres width
#define NCHUNK 49   // ceil(50000/1024)

typedef unsigned short ushort_t;
typedef __attribute__((ext_vector_type(8))) short bf16x8;
typedef __attribute__((ext_vector_type(4))) float f32x4;

__device__ __forceinline__ void atomicMaxF(float* addr, float val) {
    if (val >= 0.0f) atomicMax((int*)addr, __float_as_int(val));
    else             atomicMin((unsigned int*)addr, __float_as_uint(val));
}

__device__ __forceinline__ ushort_t f2bf(float x) {
    unsigned u = __float_as_uint(x);
    unsigned r = (u + 0x7FFFu + ((u >> 16) & 1u)) >> 16;   // RNE
    return (ushort_t)r;
}

__device__ __forceinline__ void bf2x2(unsigned u, float& lo, float& hi) {
    lo = __uint_as_float(u << 16);
    hi = __uint_as_float(u & 0xFFFF0000u);
}

__global__ void init_kernel(int* din_i, float* dout, int* cursor, float* pools) {
    int i = blockIdx.x * blockDim.x + threadIdx.x;
    if (i < Nn) { din_i[i] = 0; dout[i] = 0.0f; cursor[i] = 0; }
    if (i < Bg * 3 * Dd) pools[i] = -FLT_MAX;
}

__global__ void gather_kernel(const int* __restrict__ ids, const float* __restrict__ emb,
                              float* __restrict__ feat, ushort_t* __restrict__ feat_bf) {
    int i = blockIdx.x * blockDim.x + threadIdx.x;  // over N*32 float4s
    int n = i >> 5, c = i & 31;
    int id = ids[n];
    float4 v = ((const float4*)emb)[(size_t)id * 32 + c];
    ((float4*)feat)[(size_t)n * 32 + c] = v;
    ushort4 b;
    b.x = f2bf(v.x); b.y = f2bf(v.y); b.z = f2bf(v.z); b.w = f2bf(v.w);
    ((ushort4*)feat_bf)[(size_t)n * 32 + c] = b;
}

__global__ void maxpool_kernel(const float* __restrict__ x, float* __restrict__ pools, int col_off) {
    int b = blockIdx.x, chunk = blockIdx.y, d = threadIdx.x;
    int i0 = chunk * 125, i1 = i0 + 125;
    float mx = -FLT_MAX;
    for (int i = i0; i < i1; ++i)
        mx = fmaxf(mx, x[((size_t)(b * NPGc + i)) * Dd + d]);
    atomicMaxF(&pools[b * (3 * Dd) + col_off + d], mx);
}

// Build Wt [1536][128] bf16 (fused W_src|W_dst|W_res transposed), Wt_gc [128][128] bf16, bias_f[1536]
__global__ void prep_kernel(const float* __restrict__ W_src, const float* __restrict__ W_dst,
                            const float* __restrict__ W_res, const float* __restrict__ W_gc,
                            const float* __restrict__ b_src, const float* __restrict__ b_dst,
                            const float* __restrict__ b_res,
                            ushort_t* __restrict__ Wt, ushort_t* __restrict__ Wt_gc,
                            float* __restrict__ bias_f) {
    int i = blockIdx.x * blockDim.x + threadIdx.x;
    if (i < WNf * 128) {
        int c = i >> 7, k = i & 127;
        float v = (c < 512) ? W_src[k * 512 + c]
                : (c < 1024) ? W_dst[k * 512 + (c - 512)]
                             : W_res[k * 512 + (c - 1024)];
        Wt[i] = f2bf(v);
    } else if (i < WNf * 128 + 128 * 128) {
        int j = i - WNf * 128;
        int c = j >> 7, k = j & 127;
        Wt_gc[j] = f2bf(W_gc[k * 128 + c]);
    }
    if (i < WNf)
        bias_f[i] = (i < 512) ? b_src[i] : (i < 1024) ? b_dst[i - 512] : b_res[i - 1024];
}

// ---- Register-pipelined MFMA GEMM, NO LDS / NO barriers ----
// C[n,c] = act( A[n,:] @ Wt[c,:] + bias[c] ).  A [n_rows][128] bf16 (rows padded),
// Wt [WN][128] bf16 (pre-transposed, L2-resident).
// Block = 64 A-rows x (WN/gridDim.y) cols.  A fragments live in registers (one-time
// load, K=128).  W 64-col tiles flow global->register through a named 2-deep
// double buffer (wvA/wvB: static indices, no scratch), so the compiler can hoist
// prefetch loads across the MFMAs -- nothing to drain, no vmcnt(0) barrier stall.
// Operand-swapped MFMA => lane holds 4 consecutive C-cols => ushort4/float4 stores.
// Requires: tiles-per-block even.
__global__ __launch_bounds__(256) void mfma_gemm_kernel(
    const ushort_t* __restrict__ A, const ushort_t* __restrict__ Wt,
    const float* __restrict__ bias, ushort_t* __restrict__ Ob, float* __restrict__ Of,
    int n_rows, int WN, int do_leak)
{
    int ncols = WN >> 6;
    int ntile = ncols / gridDim.y;          // even by construction
    int ct0   = blockIdx.y * ntile;
    int row0  = blockIdx.x * 64;
    int w = threadIdx.x >> 6, lane = threadIdx.x & 63;
    int lrow = lane & 15, kg = lane >> 4;

    // one-time A fragments: av[fi][ks], rows row0+fi*16+lrow, k = ks*32+kg*8
    bf16x8 av[4][4];
    {
        const ushort_t* ap = A + (size_t)(row0 + lrow) * 128 + kg * 8;
        #pragma unroll
        for (int fi = 0; fi < 4; ++fi)
            #pragma unroll
            for (int ks = 0; ks < 4; ++ks)
                av[fi][ks] = *(const bf16x8*)(ap + fi * 16 * 128 + ks * 32);
    }

    // this wave's W slice base: row (ct*64 + w*16 + lrow), byte offset kg*16 (+ks*64)
    const ushort_t* wp = Wt + (size_t)(ct0 * 64 + w * 16 + lrow) * 128 + kg * 8;
    const size_t TSTR = 64 * 128;   // elements per 64-col tile

    auto epi = [&](int ctt, f32x4 (&acc)[4]) {
        int colb = (ct0 + ctt) * 64 + w * 16 + kg * 4;
        float4 bv4 = *(const float4*)(bias + colb);
        #pragma unroll
        for (int fi = 0; fi < 4; ++fi) {
            int grow = row0 + fi * 16 + lrow;
            if (grow < n_rows) {
                float o[4];
                #pragma unroll
                for (int j = 0; j < 4; ++j) {
                    float v = acc[fi][j] + ((const float*)&bv4)[j];
                    if (do_leak) v = v >= 0.0f ? v : 0.01f * v;
                    o[j] = v;
                }
                if (Ob) {
                    ushort4 ob;
                    ob.x = f2bf(o[0]); ob.y = f2bf(o[1]); ob.z = f2bf(o[2]); ob.w = f2bf(o[3]);
                    *(ushort4*)(Ob + (size_t)grow * WN + colb) = ob;
                } else {
                    *(float4*)(Of + (size_t)grow * WN + colb) = *(float4*)o;
                }
            }
        }
    };

    bf16x8 wvA[4], wvB[4];
    #pragma unroll
    for (int ks = 0; ks < 4; ++ks) wvA[ks] = *(const bf16x8*)(wp + ks * 32);

    for (int ct = 0; ct < ntile; ct += 2) {
        // prefetch tile ct+1 (always exists: ntile even)
        #pragma unroll
        for (int ks = 0; ks < 4; ++ks)
            wvB[ks] = *(const bf16x8*)(wp + (size_t)(ct + 1) * TSTR + ks * 32);
        {
            f32x4 acc[4] = {};
            #pragma unroll
            for (int ks = 0; ks < 4; ++ks)
                #pragma unroll
                for (int fi = 0; fi < 4; ++fi)
                    acc[fi] = __builtin_amdgcn_mfma_f32_16x16x32_bf16(wvA[ks], av[fi][ks], acc[fi], 0, 0, 0);
            epi(ct, acc);
        }
        if (ct + 2 < ntile) {
            #pragma unroll
            for (int ks = 0; ks < 4; ++ks)
                wvA[ks] = *(const bf16x8*)(wp + (size_t)(ct + 2) * TSTR + ks * 32);
        }
        {
            f32x4 acc[4] = {};
            #pragma unroll
            for (int ks = 0; ks < 4; ++ks)
                #pragma unroll
                for (int fi = 0; fi < 4; ++fi)
                    acc[fi] = __builtin_amdgcn_mfma_f32_16x16x32_bf16(wvB[ks], av[fi][ks], acc[fi], 0, 0, 0);
            epi(ct + 1, acc);
        }
    }
}

// ---- CSR build ----
__global__ void degree2_kernel(const int* __restrict__ src, const int* __restrict__ dst,
                               int* __restrict__ din_i, float* __restrict__ dout) {
    int e = blockIdx.x * blockDim.x + threadIdx.x;
    if (e >= Ee) return;
    atomicAdd(&din_i[dst[e]], 1);
    atomicAdd(&dout[src[e]], 1.0f);
}

// two-level scan: per-chunk reduce -> serial scan of 49 partials -> per-chunk scan
__global__ __launch_bounds__(256) void scan_reduce_kernel(const int* __restrict__ din_i,
                                                          int* __restrict__ partials) {
    int b = blockIdx.x, t = threadIdx.x;
    int base = b * 1024 + t * 4;
    int s = 0;
    #pragma unroll
    for (int j = 0; j < 4; ++j) { int i = base + j; if (i < Nn) s += din_i[i]; }
    #pragma unroll
    for (int off = 32; off > 0; off >>= 1) s += __shfl_xor(s, off);
    __shared__ int wsum[4];
    if ((t & 63) == 0) wsum[t >> 6] = s;
    __syncthreads();
    if (t == 0) partials[b] = wsum[0] + wsum[1] + wsum[2] + wsum[3];
}

__global__ void scan_mid_kernel(int* __restrict__ partials, int* __restrict__ row_start) {
    if (threadIdx.x == 0) {
        int acc = 0;
        for (int i = 0; i < NCHUNK; ++i) { int v = partials[i]; partials[i] = acc; acc += v; }
        row_start[Nn] = acc;
    }
}

__global__ __launch_bounds__(256) void scan_final_kernel(const int* __restrict__ din_i,
                                                         const int* __restrict__ partials,
                                                         int* __restrict__ row_start,
                                                         float* __restrict__ din_f) {
    int b = blockIdx.x, t = threadIdx.x;
    int base = b * 1024 + t * 4;
    int v[4]; int s = 0;
    #pragma unroll
    for (int j = 0; j < 4; ++j) {
        v[j] = (base + j < Nn) ? din_i[base + j] : 0;
        s += v[j];
    }
    __shared__ int buf[256];
    buf[t] = s;
    __syncthreads();
    #pragma unroll
    for (int off = 1; off < 256; off <<= 1) {
        int x = (t >= off) ? buf[t - off] : 0;
        __syncthreads();
        buf[t] += x;
        __syncthreads();
    }
    int excl = buf[t] - s + partials[b];
    #pragma unroll
    for (int j = 0; j < 4; ++j) {
        if (base + j < Nn) {
            row_start[base + j] = excl;
            din_f[base + j] = (float)v[j];
            excl += v[j];
        }
    }
}

__global__ void scatter_kernel(const int* __restrict__ src, const int* __restrict__ dst,
                               const int* __restrict__ row_start, int* __restrict__ cursor,
                               int* __restrict__ csr_src) {
    int e = blockIdx.x * blockDim.x + threadIdx.x;
    if (e >= Ee) return;
    int d = dst[e];
    int slot = row_start[d] + atomicAdd(&cursor[d], 1);
    csr_src[slot] = src[e];
}

// ---- fused GATv2: one wave per dst node, online softmax over in-edges ----
// h_all row: [hs(512) | hd(512) | rres(512)] bf16. lane l owns flat cols [8l,8l+8), head = l>>4
// Next-edge hs row is register-prefetched so the gather latency hides under the exp/fma chain.
__global__ __launch_bounds__(256) void gat_fused_kernel(
    const ushort_t* __restrict__ h_all, const float* __restrict__ attn,
    const int* __restrict__ row_start, const int* __restrict__ csr_src,
    float* __restrict__ res)
{
    int d = (blockIdx.x * 256 + threadIdx.x) >> 6;
    int lane = threadIdx.x & 63;
    if (d >= Nn) return;
    int e0 = row_start[d], e1 = row_start[d + 1];

    float hdv[8], atv[8];
    {
        uint4 hr = *(const uint4*)(h_all + (size_t)d * WNf + 512 + lane * 8);
        bf2x2(hr.x, hdv[0], hdv[1]); bf2x2(hr.y, hdv[2], hdv[3]);
        bf2x2(hr.z, hdv[4], hdv[5]); bf2x2(hr.w, hdv[6], hdv[7]);
        float4 a0 = *(const float4*)(attn + lane * 8);
        float4 a1 = *(const float4*)(attn + lane * 8 + 4);
        atv[0] = a0.x; atv[1] = a0.y; atv[2] = a0.z; atv[3] = a0.w;
        atv[4] = a1.x; atv[5] = a1.y; atv[6] = a1.z; atv[7] = a1.w;
    }

    float m = -FLT_MAX, denom = 0.0f;
    float acc[8] = {};

    int s = (e0 < e1) ? csr_src[e0] : 0;
    uint4 raw = *(const uint4*)(h_all + (size_t)s * WNf + lane * 8);
    for (int e = e0; e < e1; ++e) {
        int s_next = (e + 1 < e1) ? csr_src[e + 1] : s;
        uint4 raw_next = *(const uint4*)(h_all + (size_t)s_next * WNf + lane * 8);
        float hsv[8];
        bf2x2(raw.x, hsv[0], hsv[1]); bf2x2(raw.y, hsv[2], hsv[3]);
        bf2x2(raw.z, hsv[4], hsv[5]); bf2x2(raw.w, hsv[6], hsv[7]);
        float p = 0.0f;
        #pragma unroll
        for (int j = 0; j < 8; ++j) {
            float x = hsv[j] + hdv[j];
            x = x >= 0.0f ? x : 0.2f * x;
            p = fmaf(x, atv[j], p);
        }
        p += __shfl_xor(p, 1); p += __shfl_xor(p, 2);
        p += __shfl_xor(p, 4); p += __shfl_xor(p, 8);
        float mn = fmaxf(m, p);
        float corr = expf(m - mn);
        float ex = expf(p - mn);
        denom = denom * corr + ex;
        #pragma unroll
        for (int j = 0; j < 8; ++j) acc[j] = fmaf(acc[j], corr, hsv[j] * ex);
        m = mn;
        raw = raw_next;
    }

    float inv = (e1 > e0) ? 1.0f / denom : 0.0f;
    float rv[8];
    {
        uint4 rr = *(const uint4*)(h_all + (size_t)d * WNf + 1024 + lane * 8);
        bf2x2(rr.x, rv[0], rv[1]); bf2x2(rr.y, rv[2], rv[3]);
        bf2x2(rr.z, rv[4], rv[5]); bf2x2(rr.w, rv[6], rv[7]);
    }
    float t[8];
    #pragma unroll
    for (int j = 0; j < 8; ++j) {
        float v = fmaf(acc[j], inv, rv[j]);
        t[j] = v >= 0.0f ? v : 0.01f * v;
    }
    #pragma unroll
    for (int j = 0; j < 8; ++j) {
        t[j] += __shfl_xor(t[j], 16);
        t[j] += __shfl_xor(t[j], 32);
    }
    if (lane < 16) {
        float o0[4] = {0.25f * t[0], 0.25f * t[1], 0.25f * t[2], 0.25f * t[3]};
        float o1[4] = {0.25f * t[4], 0.25f * t[5], 0.25f * t[6], 0.25f * t[7]};
        *(float4*)(res + (size_t)d * Dd + lane * 8)     = *(float4*)o0;
        *(float4*)(res + (size_t)d * Dd + lane * 8 + 4) = *(float4*)o1;
    }
}

// ---- GraphConv aggregate via CSR; epilogue applies rsqrt(din) and emits bf16 ----
__global__ __launch_bounds__(256) void gc_gather_kernel(
    const float* __restrict__ res, const int* __restrict__ row_start,
    const int* __restrict__ csr_src, const float* __restrict__ dout,
    const float* __restrict__ din, ushort_t* __restrict__ agg_bf)
{
    int d = (blockIdx.x * 256 + threadIdx.x) >> 6;
    int lane = threadIdx.x & 63;
    if (d >= Nn) return;
    int e0 = row_start[d], e1 = row_start[d + 1];
    float ax = 0.0f, ay = 0.0f;
    int s = (e0 < e1) ? csr_src[e0] : 0;
    float sc = 1.0f / sqrtf(fmaxf((e0 < e1) ? dout[s] : 1.0f, 1.0f));
    float2 v = (e0 < e1) ? ((const float2*)(res + (size_t)s * Dd))[lane] : make_float2(0.f, 0.f);
    for (int e = e0; e < e1; ++e) {
        int s_next = (e + 1 < e1) ? csr_src[e + 1] : s;
        float sc_n = 1.0f / sqrtf(fmaxf(dout[s_next], 1.0f));
        float2 v_n = ((const float2*)(res + (size_t)s_next * Dd))[lane];
        ax = fmaf(v.x, sc, ax);
        ay = fmaf(v.y, sc, ay);
        sc = sc_n;
        v = v_n;
    }
    float scd = 1.0f / sqrtf(fmaxf(din[d], 1.0f));
    ushort2 o;
    o.x = f2bf(ax * scd);
    o.y = f2bf(ay * scd);
    ((ushort2*)(agg_bf + (size_t)d * Dd))[lane] = o;
}

__global__ void final_kernel(const float* __restrict__ pools, const float* __restrict__ W_mlp,
                             const float* __restrict__ b_mlp, float* __restrict__ out) {
    int b = blockIdx.x, lane = threadIdx.x;
    float s = 0.0f;
    for (int j = lane; j < 3 * Dd; j += 64)
        s += fmaxf(pools[b * (3 * Dd) + j], 0.0f) * W_mlp[j];
    #pragma unroll
    for (int off = 32; off > 0; off >>= 1) s += __shfl_xor(s, off);
    if (lane == 0) out[b] = s + b_mlp[0];
}

extern "C" void kernel_launch(void* const* d_in, const int* in_sizes, int n_in,
                              void* d_out, int out_size, void* d_ws, size_t ws_size,
                              hipStream_t stream) {
    const int*   node_ids = (const int*)d_in[0];
    const int*   src      = (const int*)d_in[1];
    const int*   dst      = (const int*)d_in[2];
    const float* emb      = (const float*)d_in[3];
    const float* W_src    = (const float*)d_in[4];
    const float* b_src    = (const float*)d_in[5];
    const float* W_dst    = (const float*)d_in[6];
    const float* b_dst    = (const float*)d_in[7];
    const float* attn     = (const float*)d_in[8];
    const float* W_res    = (const float*)d_in[9];
    const float* b_res    = (const float*)d_in[10];
    const float* W_gc     = (const float*)d_in[11];
    const float* b_gc     = (const float*)d_in[12];
    const float* W_mlp    = (const float*)d_in[13];
    const float* b_mlp    = (const float*)d_in[14];
    float* out = (float*)d_out;

    char* w = (char*)d_ws;
    size_t off = 0;
    float*    feat    = (float*)(w + off);    off += (size_t)Nn * Dd * 4;        // 25.6 MB
    ushort_t* feat_bf = (ushort_t*)(w + off); off += (size_t)(Nn + 64) * Dd * 2; // 12.8 MB (+pad rows)
    ushort_t* h_all   = (ushort_t*)(w + off); off += (size_t)Nn * WNf * 2;       // 153.6 MB
    ushort_t* Wt      = (ushort_t*)(w + off); off += (size_t)WNf * 128 * 2;
    ushort_t* Wt_gc   = (ushort_t*)(w + off); off += (size_t)128 * 128 * 2;
    float*    bias_f  = (float*)(w + off);    off += (size_t)WNf * 4;
    int*      csr_src = (int*)(w + off);      off += (size_t)Ee * 4;
    int*      row_st  = (int*)(w + off);      off += ((size_t)Nn + 4) * 4;
    int*      cursor  = (int*)(w + off);      off += (size_t)Nn * 4;
    int*      din_i   = (int*)(w + off);      off += (size_t)Nn * 4;
    float*    din_f   = (float*)(w + off);    off += (size_t)Nn * 4;
    float*    dout_f  = (float*)(w + off);    off += (size_t)Nn * 4;
    int*      partials= (int*)(w + off);      off += 64 * 4;
    float*    pools   = (float*)(w + off);    off += (size_t)Bg * 3 * Dd * 4;

    float*    res    = feat;                                  // feat dead after fused GEMM
    ushort_t* agg_bf = h_all;                                 // h_all dead after gat_fused
    float*    res2   = (float*)(w + (size_t)Nn * Dd * 6 + (size_t)(Nn + 64) * Dd * 2);  // inside h_all, past agg_bf

    init_kernel<<<(Nn + 255) / 256, 256, 0, stream>>>(din_i, dout_f, cursor, pools);
    gather_kernel<<<(Nn * 32) / 256, 256, 0, stream>>>(node_ids, emb, feat, feat_bf);
    maxpool_kernel<<<dim3(Bg, 50), Dd, 0, stream>>>(feat, pools, 0);

    prep_kernel<<<(WNf * 128 + 128 * 128 + 255) / 256, 256, 0, stream>>>(
        W_src, W_dst, W_res, W_gc, b_src, b_dst, b_res, Wt, Wt_gc, bias_f);

    // CSR build
    degree2_kernel<<<(Ee + 255) / 256, 256, 0, stream>>>(src, dst, din_i, dout_f);
    scan_reduce_kernel<<<NCHUNK, 256, 0, stream>>>(din_i, partials);
    scan_mid_kernel<<<1, 64, 0, stream>>>(partials, row_st);
    scan_final_kernel<<<NCHUNK, 256, 0, stream>>>(din_i, partials, row_st, din_f);
    scatter_kernel<<<(Ee + 255) / 256, 256, 0, stream>>>(src, dst, row_st, cursor, csr_src);

    // fused hs|hd|rres GEMM: 782 row-blocks x 2 col-splits (12 tiles each, even)
    mfma_gemm_kernel<<<dim3((Nn + 63) / 64, 2), 256, 0, stream>>>(
        feat_bf, Wt, bias_f, h_all, nullptr, Nn, WNf, 0);

    gat_fused_kernel<<<(Nn * 64) / 256, 256, 0, stream>>>(h_all, attn, row_st, csr_src, res);
    maxpool_kernel<<<dim3(Bg, 50), Dd, 0, stream>>>(res, pools, Dd);

    gc_gather_kernel<<<(Nn * 64) / 256, 256, 0, stream>>>(res, row_st, csr_src, dout_f, din_f, agg_bf);
    mfma_gemm_kernel<<<dim3((Nn + 63) / 64, 1), 256, 0, stream>>>(
        agg_bf, Wt_gc, b_gc, nullptr, res2, Nn, Dd, 1);
    maxpool_kernel<<<dim3(Bg, 50), Dd, 0, stream>>>(res2, pools, 2 * Dd);

    final_kernel<<<Bg, 64, 0, stream>>>(pools, W_mlp, b_mlp, out);
}

// Round 11
// 388.720 us; speedup vs baseline: 6.1016x; 1.0384x over previous
//
#include <hip/hip_runtime.h>
#include <float.h>
#include <math.h>

#define Bg   8
#define NPGc 6250
#define Hh   4
#define Dd   128
#define Nn   50000
#define Ee   400000
#define HDd  512
#define WNf  1536   // fused hs|hd|rres width
#define NCHUNK 49   // ceil(50000/1024)

typedef unsigned short ushort_t;
typedef __attribute__((ext_vector_type(8))) short bf16x8;
typedef __attribute__((ext_vector_type(4))) float f32x4;

__device__ __forceinline__ void atomicMaxF(float* addr, float val) {
    if (val >= 0.0f) atomicMax((int*)addr, __float_as_int(val));
    else             atomicMin((unsigned int*)addr, __float_as_uint(val));
}

__device__ __forceinline__ ushort_t f2bf(float x) {
    unsigned u = __float_as_uint(x);
    unsigned r = (u + 0x7FFFu + ((u >> 16) & 1u)) >> 16;   // RNE
    return (ushort_t)r;
}

__device__ __forceinline__ void bf2x2(unsigned u, float& lo, float& hi) {
    lo = __uint_as_float(u << 16);
    hi = __uint_as_float(u & 0xFFFF0000u);
}

// ---- fused setup: gather(+bf16 cast) | init | weight-transpose prep ----
__global__ void setup_kernel(const int* __restrict__ ids, const float* __restrict__ emb,
                             float* __restrict__ feat, ushort_t* __restrict__ feat_bf,
                             const float* __restrict__ W_src, const float* __restrict__ W_dst,
                             const float* __restrict__ W_res, const float* __restrict__ W_gc,
                             const float* __restrict__ b_src, const float* __restrict__ b_dst,
                             const float* __restrict__ b_res,
                             ushort_t* __restrict__ Wt, ushort_t* __restrict__ Wt_gc,
                             float* __restrict__ bias_f,
                             int* __restrict__ din_i, float* __restrict__ dout,
                             int* __restrict__ cursor, float* __restrict__ pools) {
    int i = blockIdx.x * blockDim.x + threadIdx.x;
    {   // gather: over N*32 float4s
        int n = i >> 5, c = i & 31;
        int id = ids[n];
        float4 v = ((const float4*)emb)[(size_t)id * 32 + c];
        ((float4*)feat)[(size_t)n * 32 + c] = v;
        ushort4 b;
        b.x = f2bf(v.x); b.y = f2bf(v.y); b.z = f2bf(v.z); b.w = f2bf(v.w);
        ((ushort4*)feat_bf)[(size_t)n * 32 + c] = b;
    }
    if (i < Nn) { din_i[i] = 0; dout[i] = 0.0f; cursor[i] = 0; }
    if (i < Bg * 3 * Dd) pools[i] = -FLT_MAX;
    if (i < WNf * 128) {
        int c = i >> 7, k = i & 127;
        float v = (c < 512) ? W_src[k * 512 + c]
                : (c < 1024) ? W_dst[k * 512 + (c - 512)]
                             : W_res[k * 512 + (c - 1024)];
        Wt[i] = f2bf(v);
    } else if (i < WNf * 128 + 128 * 128) {
        int j = i - WNf * 128;
        int c = j >> 7, k = j & 127;
        Wt_gc[j] = f2bf(W_gc[k * 128 + c]);
    }
    if (i < WNf)
        bias_f[i] = (i < 512) ? b_src[i] : (i < 1024) ? b_dst[i - 512] : b_res[i - 1024];
}

__global__ void maxpool_kernel(const float* __restrict__ x, float* __restrict__ pools, int col_off) {
    int b = blockIdx.x, chunk = blockIdx.y, d = threadIdx.x;
    int i0 = chunk * 125, i1 = i0 + 125;
    float mx = -FLT_MAX;
    for (int i = i0; i < i1; ++i)
        mx = fmaxf(mx, x[((size_t)(b * NPGc + i)) * Dd + d]);
    atomicMaxF(&pools[b * (3 * Dd) + col_off + d], mx);
}

// ---- Register-pipelined MFMA GEMM, NO LDS / NO barriers, compile-time NTILE ----
// C[n,c] = act( A[n,:] @ Wt[c,:] + bias[c] ).  A [n_rows][128] bf16 (rows padded),
// Wt [WN][128] bf16 (pre-transposed, L2-resident).  Block = 64 A-rows x NTILE*64 cols.
// A fragments one-time in registers (K=128).  Tile loop fully unrolled: all W loads
// are independent restrict-const loads the scheduler hoists ahead of the MFMAs,
// windowed by the launch_bounds VGPR cap (3 waves/EU).  Operand-swapped MFMA =>
// lane holds 4 consecutive C-cols => packed cvt + 8B stores.
template<int NTILE, bool LEAK, bool BF16OUT>
__global__ __launch_bounds__(256, 3) void mfma_gemm_kernel(
    const ushort_t* __restrict__ A, const ushort_t* __restrict__ Wt,
    const float* __restrict__ bias, ushort_t* __restrict__ Ob, float* __restrict__ Of,
    int n_rows, int WN)
{
    int ct0   = blockIdx.y * NTILE;
    int row0  = blockIdx.x * 64;
    int w = threadIdx.x >> 6, lane = threadIdx.x & 63;
    int lrow = lane & 15, kg = lane >> 4;

    // one-time A fragments: av[fi][ks], rows row0+fi*16+lrow, k = ks*32+kg*8
    bf16x8 av[4][4];
    {
        const ushort_t* ap = A + (size_t)(row0 + lrow) * 128 + kg * 8;
        #pragma unroll
        for (int fi = 0; fi < 4; ++fi)
            #pragma unroll
            for (int ks = 0; ks < 4; ++ks)
                av[fi][ks] = *(const bf16x8*)(ap + fi * 16 * 128 + ks * 32);
    }

    // this wave's W slice base: row (ct*64 + w*16 + lrow), elem offset kg*8 (+ks*32)
    const ushort_t* wp = Wt + (size_t)(ct0 * 64 + w * 16 + lrow) * 128 + kg * 8;
    const size_t TSTR = 64 * 128;   // elements per 64-col tile

    #pragma unroll
    for (int ct = 0; ct < NTILE; ++ct) {
        bf16x8 wv[4];
        #pragma unroll
        for (int ks = 0; ks < 4; ++ks)
            wv[ks] = *(const bf16x8*)(wp + (size_t)ct * TSTR + ks * 32);

        f32x4 acc[4] = {};
        #pragma unroll
        for (int ks = 0; ks < 4; ++ks)
            #pragma unroll
            for (int fi = 0; fi < 4; ++fi)
                acc[fi] = __builtin_amdgcn_mfma_f32_16x16x32_bf16(wv[ks], av[fi][ks], acc[fi], 0, 0, 0);

        // epilogue: lane (lrow,kg) holds C rows row0+fi*16+lrow, cols colb..colb+3
        int colb = (ct0 + ct) * 64 + w * 16 + kg * 4;
        float4 bv4 = *(const float4*)(bias + colb);
        #pragma unroll
        for (int fi = 0; fi < 4; ++fi) {
            int grow = row0 + fi * 16 + lrow;
            if (grow < n_rows) {
                float o[4];
                #pragma unroll
                for (int j = 0; j < 4; ++j) {
                    float v = acc[fi][j] + ((const float*)&bv4)[j];
                    if (LEAK) v = v >= 0.0f ? v : 0.01f * v;
                    o[j] = v;
                }
                if (BF16OUT) {
                    unsigned r0, r1;
                    asm("v_cvt_pk_bf16_f32 %0, %1, %2" : "=v"(r0) : "v"(o[0]), "v"(o[1]));
                    asm("v_cvt_pk_bf16_f32 %0, %1, %2" : "=v"(r1) : "v"(o[2]), "v"(o[3]));
                    uint2 ob; ob.x = r0; ob.y = r1;
                    *(uint2*)(Ob + (size_t)grow * WN + colb) = ob;
                } else {
                    *(float4*)(Of + (size_t)grow * WN + colb) = *(float4*)o;
                }
            }
        }
    }
}

// ---- CSR build ----
__global__ void degree2_kernel(const int* __restrict__ src, const int* __restrict__ dst,
                               int* __restrict__ din_i, float* __restrict__ dout) {
    int e = blockIdx.x * blockDim.x + threadIdx.x;
    if (e >= Ee) return;
    atomicAdd(&din_i[dst[e]], 1);
    atomicAdd(&dout[src[e]], 1.0f);
}

// two-level scan: per-chunk reduce -> serial scan of 49 partials -> per-chunk scan
__global__ __launch_bounds__(256) void scan_reduce_kernel(const int* __restrict__ din_i,
                                                          int* __restrict__ partials) {
    int b = blockIdx.x, t = threadIdx.x;
    int base = b * 1024 + t * 4;
    int s = 0;
    #pragma unroll
    for (int j = 0; j < 4; ++j) { int i = base + j; if (i < Nn) s += din_i[i]; }
    #pragma unroll
    for (int off = 32; off > 0; off >>= 1) s += __shfl_xor(s, off);
    __shared__ int wsum[4];
    if ((t & 63) == 0) wsum[t >> 6] = s;
    __syncthreads();
    if (t == 0) partials[b] = wsum[0] + wsum[1] + wsum[2] + wsum[3];
}

__global__ void scan_mid_kernel(int* __restrict__ partials, int* __restrict__ row_start) {
    if (threadIdx.x == 0) {
        int acc = 0;
        for (int i = 0; i < NCHUNK; ++i) { int v = partials[i]; partials[i] = acc; acc += v; }
        row_start[Nn] = acc;
    }
}

__global__ __launch_bounds__(256) void scan_final_kernel(const int* __restrict__ din_i,
                                                         const int* __restrict__ partials,
                                                         int* __restrict__ row_start,
                                                         float* __restrict__ din_f) {
    int b = blockIdx.x, t = threadIdx.x;
    int base = b * 1024 + t * 4;
    int v[4]; int s = 0;
    #pragma unroll
    for (int j = 0; j < 4; ++j) {
        v[j] = (base + j < Nn) ? din_i[base + j] : 0;
        s += v[j];
    }
    __shared__ int buf[256];
    buf[t] = s;
    __syncthreads();
    #pragma unroll
    for (int off = 1; off < 256; off <<= 1) {
        int x = (t >= off) ? buf[t - off] : 0;
        __syncthreads();
        buf[t] += x;
        __syncthreads();
    }
    int excl = buf[t] - s + partials[b];
    #pragma unroll
    for (int j = 0; j < 4; ++j) {
        if (base + j < Nn) {
            row_start[base + j] = excl;
            din_f[base + j] = (float)v[j];
            excl += v[j];
        }
    }
}

__global__ void scatter_kernel(const int* __restrict__ src, const int* __restrict__ dst,
                               const int* __restrict__ row_start, int* __restrict__ cursor,
                               int* __restrict__ csr_src) {
    int e = blockIdx.x * blockDim.x + threadIdx.x;
    if (e >= Ee) return;
    int d = dst[e];
    int slot = row_start[d] + atomicAdd(&cursor[d], 1);
    csr_src[slot] = src[e];
}

// ---- fused GATv2: one wave per dst node, online softmax over in-edges ----
// h_all row: [hs(512) | hd(512) | rres(512)] bf16. lane l owns flat cols [8l,8l+8), head = l>>4
// Next-edge hs row is register-prefetched so the gather latency hides under the exp/fma chain.
__global__ __launch_bounds__(256) void gat_fused_kernel(
    const ushort_t* __restrict__ h_all, const float* __restrict__ attn,
    const int* __restrict__ row_start, const int* __restrict__ csr_src,
    float* __restrict__ res)
{
    int d = (blockIdx.x * 256 + threadIdx.x) >> 6;
    int lane = threadIdx.x & 63;
    if (d >= Nn) return;
    int e0 = row_start[d], e1 = row_start[d + 1];

    float hdv[8], atv[8];
    {
        uint4 hr = *(const uint4*)(h_all + (size_t)d * WNf + 512 + lane * 8);
        bf2x2(hr.x, hdv[0], hdv[1]); bf2x2(hr.y, hdv[2], hdv[3]);
        bf2x2(hr.z, hdv[4], hdv[5]); bf2x2(hr.w, hdv[6], hdv[7]);
        float4 a0 = *(const float4*)(attn + lane * 8);
        float4 a1 = *(const float4*)(attn + lane * 8 + 4);
        atv[0] = a0.x; atv[1] = a0.y; atv[2] = a0.z; atv[3] = a0.w;
        atv[4] = a1.x; atv[5] = a1.y; atv[6] = a1.z; atv[7] = a1.w;
    }

    float m = -FLT_MAX, denom = 0.0f;
    float acc[8] = {};

    int s = (e0 < e1) ? csr_src[e0] : 0;
    uint4 raw = *(const uint4*)(h_all + (size_t)s * WNf + lane * 8);
    for (int e = e0; e < e1; ++e) {
        int s_next = (e + 1 < e1) ? csr_src[e + 1] : s;
        uint4 raw_next = *(const uint4*)(h_all + (size_t)s_next * WNf + lane * 8);
        float hsv[8];
        bf2x2(raw.x, hsv[0], hsv[1]); bf2x2(raw.y, hsv[2], hsv[3]);
        bf2x2(raw.z, hsv[4], hsv[5]); bf2x2(raw.w, hsv[6], hsv[7]);
        float p = 0.0f;
        #pragma unroll
        for (int j = 0; j < 8; ++j) {
            float x = hsv[j] + hdv[j];
            x = x >= 0.0f ? x : 0.2f * x;
            p = fmaf(x, atv[j], p);
        }
        p += __shfl_xor(p, 1); p += __shfl_xor(p, 2);
        p += __shfl_xor(p, 4); p += __shfl_xor(p, 8);
        float mn = fmaxf(m, p);
        float corr = expf(m - mn);
        float ex = expf(p - mn);
        denom = denom * corr + ex;
        #pragma unroll
        for (int j = 0; j < 8; ++j) acc[j] = fmaf(acc[j], corr, hsv[j] * ex);
        m = mn;
        raw = raw_next;
    }

    float inv = (e1 > e0) ? 1.0f / denom : 0.0f;
    float rv[8];
    {
        uint4 rr = *(const uint4*)(h_all + (size_t)d * WNf + 1024 + lane * 8);
        bf2x2(rr.x, rv[0], rv[1]); bf2x2(rr.y, rv[2], rv[3]);
        bf2x2(rr.z, rv[4], rv[5]); bf2x2(rr.w, rv[6], rv[7]);
    }
    float t[8];
    #pragma unroll
    for (int j = 0; j < 8; ++j) {
        float v = fmaf(acc[j], inv, rv[j]);
        t[j] = v >= 0.0f ? v : 0.01f * v;
    }
    #pragma unroll
    for (int j = 0; j < 8; ++j) {
        t[j] += __shfl_xor(t[j], 16);
        t[j] += __shfl_xor(t[j], 32);
    }
    if (lane < 16) {
        float o0[4] = {0.25f * t[0], 0.25f * t[1], 0.25f * t[2], 0.25f * t[3]};
        float o1[4] = {0.25f * t[4], 0.25f * t[5], 0.25f * t[6], 0.25f * t[7]};
        *(float4*)(res + (size_t)d * Dd + lane * 8)     = *(float4*)o0;
        *(float4*)(res + (size_t)d * Dd + lane * 8 + 4) = *(float4*)o1;
    }
}

// ---- GraphConv aggregate via CSR; epilogue applies rsqrt(din) and emits bf16 ----
__global__ __launch_bounds__(256) void gc_gather_kernel(
    const float* __restrict__ res, const int* __restrict__ row_start,
    const int* __restrict__ csr_src, const float* __restrict__ dout,
    const float* __restrict__ din, ushort_t* __restrict__ agg_bf)
{
    int d = (blockIdx.x * 256 + threadIdx.x) >> 6;
    int lane = threadIdx.x & 63;
    if (d >= Nn) return;
    int e0 = row_start[d], e1 = row_start[d + 1];
    float ax = 0.0f, ay = 0.0f;
    int s = (e0 < e1) ? csr_src[e0] : 0;
    float sc = 1.0f / sqrtf(fmaxf((e0 < e1) ? dout[s] : 1.0f, 1.0f));
    float2 v = (e0 < e1) ? ((const float2*)(res + (size_t)s * Dd))[lane] : make_float2(0.f, 0.f);
    for (int e = e0; e < e1; ++e) {
        int s_next = (e + 1 < e1) ? csr_src[e + 1] : s;
        float sc_n = 1.0f / sqrtf(fmaxf(dout[s_next], 1.0f));
        float2 v_n = ((const float2*)(res + (size_t)s_next * Dd))[lane];
        ax = fmaf(v.x, sc, ax);
        ay = fmaf(v.y, sc, ay);
        sc = sc_n;
        v = v_n;
    }
    float scd = 1.0f / sqrtf(fmaxf(din[d], 1.0f));
    ushort2 o;
    o.x = f2bf(ax * scd);
    o.y = f2bf(ay * scd);
    ((ushort2*)(agg_bf + (size_t)d * Dd))[lane] = o;
}

__global__ void final_kernel(const float* __restrict__ pools, const float* __restrict__ W_mlp,
                             const float* __restrict__ b_mlp, float* __restrict__ out) {
    int b = blockIdx.x, lane = threadIdx.x;
    float s = 0.0f;
    for (int j = lane; j < 3 * Dd; j += 64)
        s += fmaxf(pools[b * (3 * Dd) + j], 0.0f) * W_mlp[j];
    #pragma unroll
    for (int off = 32; off > 0; off >>= 1) s += __shfl_xor(s, off);
    if (lane == 0) out[b] = s + b_mlp[0];
}

extern "C" void kernel_launch(void* const* d_in, const int* in_sizes, int n_in,
                              void* d_out, int out_size, void* d_ws, size_t ws_size,
                              hipStream_t stream) {
    const int*   node_ids = (const int*)d_in[0];
    const int*   src      = (const int*)d_in[1];
    const int*   dst      = (const int*)d_in[2];
    const float* emb      = (const float*)d_in[3];
    const float* W_src    = (const float*)d_in[4];
    const float* b_src    = (const float*)d_in[5];
    const float* W_dst    = (const float*)d_in[6];
    const float* b_dst    = (const float*)d_in[7];
    const float* attn     = (const float*)d_in[8];
    const float* W_res    = (const float*)d_in[9];
    const float* b_res    = (const float*)d_in[10];
    const float* W_gc     = (const float*)d_in[11];
    const float* b_gc     = (const float*)d_in[12];
    const float* W_mlp    = (const float*)d_in[13];
    const float* b_mlp    = (const float*)d_in[14];
    float* out = (float*)d_out;

    char* w = (char*)d_ws;
    size_t off = 0;
    float*    feat    = (float*)(w + off);    off += (size_t)Nn * Dd * 4;        // 25.6 MB
    ushort_t* feat_bf = (ushort_t*)(w + off); off += (size_t)(Nn + 64) * Dd * 2; // 12.8 MB (+pad rows)
    ushort_t* h_all   = (ushort_t*)(w + off); off += (size_t)Nn * WNf * 2;       // 153.6 MB
    ushort_t* Wt      = (ushort_t*)(w + off); off += (size_t)WNf * 128 * 2;
    ushort_t* Wt_gc   = (ushort_t*)(w + off); off += (size_t)128 * 128 * 2;
    float*    bias_f  = (float*)(w + off);    off += (size_t)WNf * 4;
    int*      csr_src = (int*)(w + off);      off += (size_t)Ee * 4;
    int*      row_st  = (int*)(w + off);      off += ((size_t)Nn + 4) * 4;
    int*      cursor  = (int*)(w + off);      off += (size_t)Nn * 4;
    int*      din_i   = (int*)(w + off);      off += (size_t)Nn * 4;
    float*    din_f   = (float*)(w + off);    off += (size_t)Nn * 4;
    float*    dout_f  = (float*)(w + off);    off += (size_t)Nn * 4;
    int*      partials= (int*)(w + off);      off += 64 * 4;
    float*    pools   = (float*)(w + off);    off += (size_t)Bg * 3 * Dd * 4;

    float*    res    = feat;                                  // feat dead after fused GEMM
    ushort_t* agg_bf = h_all;                                 // h_all dead after gat_fused
    float*    res2   = (float*)(w + (size_t)Nn * Dd * 6 + (size_t)(Nn + 64) * Dd * 2);  // inside h_all, past agg_bf

    setup_kernel<<<(Nn * 32) / 256, 256, 0, stream>>>(
        node_ids, emb, feat, feat_bf, W_src, W_dst, W_res, W_gc,
        b_src, b_dst, b_res, Wt, Wt_gc, bias_f, din_i, dout_f, cursor, pools);
    maxpool_kernel<<<dim3(Bg, 50), Dd, 0, stream>>>(feat, pools, 0);

    // CSR build
    degree2_kernel<<<(Ee + 255) / 256, 256, 0, stream>>>(src, dst, din_i, dout_f);
    scan_reduce_kernel<<<NCHUNK, 256, 0, stream>>>(din_i, partials);
    scan_mid_kernel<<<1, 64, 0, stream>>>(partials, row_st);
    scan_final_kernel<<<NCHUNK, 256, 0, stream>>>(din_i, partials, row_st, din_f);
    scatter_kernel<<<(Ee + 255) / 256, 256, 0, stream>>>(src, dst, row_st, cursor, csr_src);

    // fused hs|hd|rres GEMM: 782 row-blocks x 2 col-splits (12 tiles each, static unroll)
    mfma_gemm_kernel<12, false, true><<<dim3((Nn + 63) / 64, 2), 256, 0, stream>>>(
        feat_bf, Wt, bias_f, h_all, nullptr, Nn, WNf);

    gat_fused_kernel<<<(Nn * 64) / 256, 256, 0, stream>>>(h_all, attn, row_st, csr_src, res);
    maxpool_kernel<<<dim3(Bg, 50), Dd, 0, stream>>>(res, pools, Dd);

    gc_gather_kernel<<<(Nn * 64) / 256, 256, 0, stream>>>(res, row_st, csr_src, dout_f, din_f, agg_bf);
    mfma_gemm_kernel<2, true, false><<<dim3((Nn + 63) / 64, 1), 256, 0, stream>>>(
        agg_bf, Wt_gc, b_gc, nullptr, res2, Nn, Dd);
    maxpool_kernel<<<dim3(Bg, 50), Dd, 0, stream>>>(res2, pools, 2 * Dd);

    final_kernel<<<Bg, 64, 0, stream>>>(pools, W_mlp, b_mlp, out);
}